// Round 1
// baseline (996.531 us; speedup 1.0000x reference)
//
#include <hip/hip_runtime.h>
#include <stdint.h>

#define BTOK 16384
#define DM   512
#define DFF  2048
#define NE   8
#define NPAIR (BTOK*2)
#define BM 128
#define BN 128
#define BK 64
#define MAXTILES 264

typedef short s16x8 __attribute__((ext_vector_type(8)));   // 8 bf16 in 4 VGPRs
typedef float f32x4 __attribute__((ext_vector_type(4)));

// fp32 -> bf16 RNE (inputs finite)
__device__ __forceinline__ uint16_t f2b(float f) {
  uint32_t u = __float_as_uint(f);
  u += 0x7fff + ((u >> 16) & 1);
  return (uint16_t)(u >> 16);
}

// async global->LDS, 16B per lane; lds ptr must be wave-uniform base (HW adds lane*16)
__device__ __forceinline__ void g2l16(const void* gp, void* lp) {
  __builtin_amdgcn_global_load_lds(
      (__attribute__((address_space(1))) void*)(void*)gp,
      (__attribute__((address_space(3))) void*)lp, 16, 0, 0);
}

// ---------------- fp32 -> bf16 convert (8 elems/thread) ----------------
__global__ void k_cvt(const float* __restrict__ in, uint16_t* __restrict__ out, int n8) {
  int i = blockIdx.x * 256 + threadIdx.x;
  if (i >= n8) return;
  const float4* p = (const float4*)in + (size_t)i * 2;
  float4 a = p[0], b = p[1];
  uint16_t v[8] = {f2b(a.x), f2b(a.y), f2b(a.z), f2b(a.w),
                   f2b(b.x), f2b(b.y), f2b(b.z), f2b(b.w)};
  *(s16x8*)(out + (size_t)i * 8) = *(s16x8*)v;
}

// ---------- per-expert transpose+convert: in [E][R][C] fp32 -> out [E][C][R] bf16 ----------
__global__ void k_tr(const float* __restrict__ in, uint16_t* __restrict__ out, int R, int C) {
  __shared__ float t[32][33];
  int e = blockIdx.z;
  const float* src = in + (size_t)e * R * C;
  uint16_t* dst = out + (size_t)e * R * C;
  int c0 = blockIdx.x * 32, r0 = blockIdx.y * 32;
  int tx = threadIdx.x, ty = threadIdx.y;
#pragma unroll
  for (int j = 0; j < 4; j++)
    t[ty + j * 8][tx] = src[(size_t)(r0 + ty + j * 8) * C + c0 + tx];
  __syncthreads();
#pragma unroll
  for (int j = 0; j < 4; j++)
    dst[(size_t)(c0 + ty + j * 8) * R + r0 + tx] = f2b(t[tx][ty + j * 8]);
}

// ---------------- gate: fp32 logits -> softmax -> top-2 (one wave/token) ----------------
__global__ void k_route(const float* __restrict__ x, const float* __restrict__ wg,
                        int* __restrict__ counts, int* __restrict__ tk_e, float* __restrict__ tk_w) {
  int lane = threadIdx.x & 63;
  int tok = blockIdx.x * 4 + (threadIdx.x >> 6);
  const float* xr = x + (size_t)tok * DM;
  float acc[NE];
#pragma unroll
  for (int e = 0; e < NE; e++) acc[e] = 0.f;
  for (int d = lane; d < DM; d += 64) {
    float xv = xr[d];
    const float* wr = wg + (size_t)d * NE;
#pragma unroll
    for (int e = 0; e < NE; e++) acc[e] += xv * wr[e];
  }
#pragma unroll
  for (int e = 0; e < NE; e++) {
#pragma unroll
    for (int off = 32; off > 0; off >>= 1) acc[e] += __shfl_down(acc[e], off, 64);
  }
  if (lane == 0) {
    float mx = acc[0];
    for (int e = 1; e < NE; e++) mx = fmaxf(mx, acc[e]);
    float p[NE], s = 0.f;
    for (int e = 0; e < NE; e++) { p[e] = __expf(acc[e] - mx); s += p[e]; }
    float inv = 1.f / s;
    int e0 = 0; float v0 = p[0];
    for (int e = 1; e < NE; e++) if (p[e] > v0) { v0 = p[e]; e0 = e; }   // strict > = lowest-index tiebreak (top_k semantics)
    int e1 = -1; float v1 = -1.f;
    for (int e = 0; e < NE; e++) if (e != e0 && p[e] > v1) { v1 = p[e]; e1 = e; }
    tk_e[tok * 2]     = e0; tk_w[tok * 2]     = v0 * inv;
    tk_e[tok * 2 + 1] = e1; tk_w[tok * 2 + 1] = v1 * inv;
    atomicAdd(&counts[e0], 1);
    atomicAdd(&counts[e1], 1);
  }
}

// ---------------- prefix sums + tile map (single thread; E=8, <=263 tiles) ----------------
__global__ void k_setup(const int* __restrict__ counts, int* __restrict__ offsets,
                        int* __restrict__ tile_e, int* __restrict__ tile_r0, int* __restrict__ ntiles) {
  if (threadIdx.x != 0 || blockIdx.x != 0) return;
  int off = 0;
  for (int e = 0; e < NE; e++) { offsets[e] = off; off += counts[e]; }
  offsets[NE] = off;  // == NPAIR
  int nt = 0;
  for (int e = 0; e < NE; e++)
    for (int r = offsets[e]; r < offsets[e + 1]; r += BM) { tile_e[nt] = e; tile_r0[nt] = r; nt++; }
  *ntiles = nt;
}

// ---------------- build compact slot lists ----------------
__global__ void k_build(const int* __restrict__ tk_e, const float* __restrict__ tk_w,
                        const int* __restrict__ offsets, int* __restrict__ cursors,
                        int* __restrict__ tok_of, float* __restrict__ w_of) {
  int i = blockIdx.x * 256 + threadIdx.x;   // pair index
  int e = tk_e[i];
  int pos = atomicAdd(&cursors[e], 1);
  int slot = offsets[e] + pos;
  tok_of[slot] = i >> 1;
  w_of[slot] = tk_w[i];
}

// ---------------- GEMM1: h[slot][DFF] = relu(x[tok] @ W1[e] + b1[e])  (bf16, 128x128x64) ----------------
__global__ __launch_bounds__(256) void k_gemm1(
    const uint16_t* __restrict__ xb, const uint16_t* __restrict__ w1t,
    const float* __restrict__ b1,
    const int* __restrict__ tok_of, const int* __restrict__ offsets,
    const int* __restrict__ tile_e, const int* __restrict__ tile_r0,
    const int* __restrict__ ntiles, uint16_t* __restrict__ h) {
  __shared__ uint16_t smem[16384];          // sA 16KB | sB 16KB; reused for epilogue repack
  int t = blockIdx.x;
  if (t >= *ntiles) return;
  int e = tile_e[t], row0 = tile_r0[t], end = offsets[e + 1];
  int n0 = blockIdx.y * BN;
  int tid = threadIdx.x, lane = tid & 63, wave = tid >> 6;
  int wr = (wave >> 1) * 64, wc = (wave & 1) * 64;
  uint16_t* sA = smem;
  uint16_t* sB = smem + 8192;

  size_t abase[4], bbofs[4];
#pragma unroll
  for (int it = 0; it < 4; it++) {
    int chunk = it * 256 + tid;             // 1024 chunks of 8 bf16 = [128 rows][8 colchunks]
    int row = chunk >> 3, cc = chunk & 7;
    int slot = row0 + row; if (slot >= end) slot = row0;      // clamp: safe read, masked at store
    abase[it] = (size_t)tok_of[slot] * DM + (size_t)cc * 8;
    bbofs[it] = (size_t)row * DM + (size_t)cc * 8;
  }
  const uint16_t* bb = w1t + (size_t)e * DFF * DM + (size_t)n0 * DM;

  f32x4 acc[4][4];
#pragma unroll
  for (int r = 0; r < 4; r++)
#pragma unroll
    for (int c = 0; c < 4; c++)
#pragma unroll
      for (int i = 0; i < 4; i++) acc[r][c][i] = 0.f;

  for (int k0 = 0; k0 < DM; k0 += BK) {
#pragma unroll
    for (int it = 0; it < 4; it++)
      g2l16(xb + abase[it] + k0, sA + (size_t)(it * 256 + wave * 64) * 8);
#pragma unroll
    for (int it = 0; it < 4; it++)
      g2l16(bb + bbofs[it] + k0, sB + (size_t)(it * 256 + wave * 64) * 8);
    __syncthreads();
#pragma unroll
    for (int ks = 0; ks < BK; ks += 32) {
      int kk = ks + (lane >> 4) * 8;
      s16x8 af[4], bf[4];
#pragma unroll
      for (int r = 0; r < 4; r++) af[r] = *(const s16x8*)(sA + (wr + r * 16 + (lane & 15)) * BK + kk);
#pragma unroll
      for (int c = 0; c < 4; c++) bf[c] = *(const s16x8*)(sB + (wc + c * 16 + (lane & 15)) * BK + kk);
#pragma unroll
      for (int r = 0; r < 4; r++)
#pragma unroll
        for (int c = 0; c < 4; c++)
          acc[r][c] = __builtin_amdgcn_mfma_f32_16x16x32_bf16(af[r], bf[c], acc[r][c], 0, 0, 0);
    }
    __syncthreads();
  }

  // epilogue: bias+relu -> bf16 via LDS repack -> coalesced 16B stores
  float bv[4];
#pragma unroll
  for (int c = 0; c < 4; c++) bv[c] = b1[(size_t)e * DFF + n0 + wc + c * 16 + (lane & 15)];
  uint16_t* myreg = smem + wave * 4096;     // per-wave 64x64 bf16 region
#pragma unroll
  for (int r = 0; r < 4; r++)
#pragma unroll
    for (int c = 0; c < 4; c++)
#pragma unroll
      for (int i = 0; i < 4; i++) {
        int row = r * 16 + (lane >> 4) * 4 + i;           // C/D layout: col=lane&15, row=quad*4+reg
        int col = c * 16 + (lane & 15);
        float v = fmaxf(acc[r][c][i] + bv[c], 0.f);
        myreg[row * 64 + col] = f2b(v);
      }
  __syncthreads();
#pragma unroll
  for (int it = 0; it < 8; it++) {
    int chunk = it * 256 + tid;             // 2048 chunks of 8 bf16 over the 128x128 tile
    int row = chunk >> 4, cc = chunk & 15;
    int slot = row0 + row;
    if (slot < end) {
      int wv = (row >> 6) * 2 + (cc >> 3);
      const uint16_t* src = smem + wv * 4096 + (row & 63) * 64 + (cc & 7) * 8;
      *(s16x8*)(h + (size_t)slot * DFF + n0 + cc * 8) = *(const s16x8*)src;
    }
  }
}

// ---------------- GEMM2: out[tok] += w * (h[slot] @ W2[e] + b2[e]) ----------------
__global__ __launch_bounds__(256) void k_gemm2(
    const uint16_t* __restrict__ h, const uint16_t* __restrict__ w2t,
    const float* __restrict__ b2,
    const int* __restrict__ tok_of, const float* __restrict__ w_of,
    const int* __restrict__ offsets,
    const int* __restrict__ tile_e, const int* __restrict__ tile_r0,
    const int* __restrict__ ntiles, float* __restrict__ out) {
  __shared__ uint16_t smem[16384];
  int t = blockIdx.x;
  if (t >= *ntiles) return;
  int e = tile_e[t], row0 = tile_r0[t], end = offsets[e + 1];
  int n0 = blockIdx.y * BN;
  int tid = threadIdx.x, lane = tid & 63, wave = tid >> 6;
  int wr = (wave >> 1) * 64, wc = (wave & 1) * 64;
  uint16_t* sA = smem;
  uint16_t* sB = smem + 8192;

  size_t abase[4], bbofs[4];
#pragma unroll
  for (int it = 0; it < 4; it++) {
    int chunk = it * 256 + tid;
    int row = chunk >> 3, cc = chunk & 7;
    int slot = row0 + row; if (slot >= end) slot = row0;
    abase[it] = (size_t)slot * DFF + (size_t)cc * 8;
    bbofs[it] = (size_t)row * DFF + (size_t)cc * 8;
  }
  const uint16_t* bb = w2t + (size_t)e * DM * DFF + (size_t)n0 * DFF;

  f32x4 acc[4][4];
#pragma unroll
  for (int r = 0; r < 4; r++)
#pragma unroll
    for (int c = 0; c < 4; c++)
#pragma unroll
      for (int i = 0; i < 4; i++) acc[r][c][i] = 0.f;

  for (int k0 = 0; k0 < DFF; k0 += BK) {
#pragma unroll
    for (int it = 0; it < 4; it++)
      g2l16(h + abase[it] + k0, sA + (size_t)(it * 256 + wave * 64) * 8);
#pragma unroll
    for (int it = 0; it < 4; it++)
      g2l16(bb + bbofs[it] + k0, sB + (size_t)(it * 256 + wave * 64) * 8);
    __syncthreads();
#pragma unroll
    for (int ks = 0; ks < BK; ks += 32) {
      int kk = ks + (lane >> 4) * 8;
      s16x8 af[4], bf[4];
#pragma unroll
      for (int r = 0; r < 4; r++) af[r] = *(const s16x8*)(sA + (wr + r * 16 + (lane & 15)) * BK + kk);
#pragma unroll
      for (int c = 0; c < 4; c++) bf[c] = *(const s16x8*)(sB + (wc + c * 16 + (lane & 15)) * BK + kk);
#pragma unroll
      for (int r = 0; r < 4; r++)
#pragma unroll
        for (int c = 0; c < 4; c++)
          acc[r][c] = __builtin_amdgcn_mfma_f32_16x16x32_bf16(af[r], bf[c], acc[r][c], 0, 0, 0);
    }
    __syncthreads();
  }

  float bv[4];
#pragma unroll
  for (int c = 0; c < 4; c++) bv[c] = b2[(size_t)e * DM + n0 + wc + c * 16 + (lane & 15)];
#pragma unroll
  for (int r = 0; r < 4; r++)
#pragma unroll
    for (int i = 0; i < 4; i++) {
      int rowg = wr + r * 16 + (lane >> 4) * 4 + i;
      int slot = row0 + rowg;
      if (slot < end) {
        int tok = tok_of[slot];
        float wgt = w_of[slot];
        float* orow = out + (size_t)tok * DM + n0 + wc + (lane & 15);
#pragma unroll
        for (int c = 0; c < 4; c++)
          atomicAdd(orow + c * 16, wgt * (acc[r][c][i] + bv[c]));
      }
    }
}

extern "C" void kernel_launch(void* const* d_in, const int* in_sizes, int n_in,
                              void* d_out, int out_size, void* d_ws, size_t ws_size,
                              hipStream_t stream) {
  const float* x  = (const float*)d_in[0];
  const float* wg = (const float*)d_in[1];
  const float* w1 = (const float*)d_in[2];
  const float* b1 = (const float*)d_in[3];
  const float* w2 = (const float*)d_in[4];
  const float* b2 = (const float*)d_in[5];
  float* out = (float*)d_out;

  // workspace layout (~186 MB)
  char* ws = (char*)d_ws;
  uint16_t* xb   = (uint16_t*)ws;                                  // 16 MB
  uint16_t* w1t  = (uint16_t*)(ws + 16777216);                     // 16 MB  [E][DFF][DM]
  uint16_t* w2t  = (uint16_t*)(ws + 2 * 16777216);                 // 16 MB  [E][DM][DFF]
  uint16_t* hbuf = (uint16_t*)(ws + 3 * 16777216);                 // 128 MB [NPAIR][DFF]
  int* ctrl = (int*)(ws + 3 * 16777216 + 134217728);
  int*   counts  = ctrl;                 // 8
  int*   cursors = ctrl + 8;             // 8
  int*   offsets = ctrl + 16;            // 9
  int*   ntiles  = ctrl + 25;            // 1
  int*   tile_e  = ctrl + 32;            // 264
  int*   tile_r0 = ctrl + 296;           // 264
  int*   tk_e    = ctrl + 560;           // 32768
  float* tk_w    = (float*)(ctrl + 560 + 32768);
  int*   tok_of  = ctrl + 560 + 2 * 32768;
  float* w_of    = (float*)(ctrl + 560 + 3 * 32768);

  hipMemsetAsync(d_out, 0, (size_t)out_size * sizeof(float), stream);  // atomics accumulate into zeros
  hipMemsetAsync(counts, 0, 16 * sizeof(int), stream);                 // counts + cursors

  k_cvt<<<4096, 256, 0, stream>>>(x, xb, (BTOK * DM) / 8);
  k_tr<<<dim3(DFF / 32, DM / 32, NE), dim3(32, 8), 0, stream>>>(w1, w1t, DM, DFF);
  k_tr<<<dim3(DM / 32, DFF / 32, NE), dim3(32, 8), 0, stream>>>(w2, w2t, DFF, DM);
  k_route<<<BTOK / 4, 256, 0, stream>>>(x, wg, counts, tk_e, tk_w);
  k_setup<<<1, 64, 0, stream>>>(counts, offsets, tile_e, tile_r0, ntiles);
  k_build<<<NPAIR / 256, 256, 0, stream>>>(tk_e, tk_w, offsets, cursors, tok_of, w_of);
  k_gemm1<<<dim3(MAXTILES, DFF / BN), 256, 0, stream>>>(xb, w1t, b1, tok_of, offsets,
                                                        tile_e, tile_r0, ntiles, hbuf);
  k_gemm2<<<dim3(MAXTILES, DM / BN), 256, 0, stream>>>(hbuf, w2t, b2, tok_of, w_of, offsets,
                                                       tile_e, tile_r0, ntiles, out);
}

// Round 2
// 493.179 us; speedup vs baseline: 2.0206x; 2.0206x over previous
//
#include <hip/hip_runtime.h>
#include <stdint.h>

#define BTOK 16384
#define DM   512
#define DFF  2048
#define NE   8
#define NPAIR (BTOK*2)
#define BM 128
#define BN 128
#define BK 64
#define MAXTILES 264

typedef short s16x8 __attribute__((ext_vector_type(8)));   // 8 bf16 in 4 VGPRs
typedef float f32x4 __attribute__((ext_vector_type(4)));

// fp32 -> bf16 RNE (inputs finite)
__device__ __forceinline__ uint16_t f2b(float f) {
  uint32_t u = __float_as_uint(f);
  u += 0x7fff + ((u >> 16) & 1);
  return (uint16_t)(u >> 16);
}

// async global->LDS, 16B per lane; lds ptr must be wave-uniform base (HW adds lane*16)
__device__ __forceinline__ void g2l16(const void* gp, void* lp) {
  __builtin_amdgcn_global_load_lds(
      (__attribute__((address_space(1))) void*)(void*)gp,
      (__attribute__((address_space(3))) void*)lp, 16, 0, 0);
}

// ---------------- fp32 -> bf16 convert (8 elems/thread) ----------------
__global__ void k_cvt(const float* __restrict__ in, uint16_t* __restrict__ out, int n8) {
  int i = blockIdx.x * 256 + threadIdx.x;
  if (i >= n8) return;
  const float4* p = (const float4*)in + (size_t)i * 2;
  float4 a = p[0], b = p[1];
  uint16_t v[8] = {f2b(a.x), f2b(a.y), f2b(a.z), f2b(a.w),
                   f2b(b.x), f2b(b.y), f2b(b.z), f2b(b.w)};
  *(s16x8*)(out + (size_t)i * 8) = *(s16x8*)v;
}

// ---------- per-expert transpose+convert: in [E][R][C] fp32 -> out [E][C][R] bf16 ----------
__global__ void k_tr(const float* __restrict__ in, uint16_t* __restrict__ out, int R, int C) {
  __shared__ float t[32][33];
  int e = blockIdx.z;
  const float* src = in + (size_t)e * R * C;
  uint16_t* dst = out + (size_t)e * R * C;
  int c0 = blockIdx.x * 32, r0 = blockIdx.y * 32;
  int tx = threadIdx.x, ty = threadIdx.y;
#pragma unroll
  for (int j = 0; j < 4; j++)
    t[ty + j * 8][tx] = src[(size_t)(r0 + ty + j * 8) * C + c0 + tx];
  __syncthreads();
#pragma unroll
  for (int j = 0; j < 4; j++)
    dst[(size_t)(c0 + ty + j * 8) * R + r0 + tx] = f2b(t[tx][ty + j * 8]);
}

// ---- gate: wave-per-token x16, wg in registers, LDS histogram, 8 global atomics/block ----
__global__ __launch_bounds__(256) void k_route(const float* __restrict__ x,
                                               const float* __restrict__ wg,
                                               int* __restrict__ counts,
                                               int* __restrict__ tk_e, float* __restrict__ tk_w) {
  __shared__ int hist[NE];
  int tid = threadIdx.x, lane = tid & 63, wave = tid >> 6;
  if (tid < NE) hist[tid] = 0;
  __syncthreads();

  // each lane holds wg rows d = j*64+lane, all 8 experts, in registers (64 VGPRs)
  float wv[8][8];
#pragma unroll
  for (int j = 0; j < 8; j++) {
    const float4* wr = (const float4*)(wg + (size_t)(j * 64 + lane) * NE);
    float4 a = wr[0], b = wr[1];
    wv[j][0] = a.x; wv[j][1] = a.y; wv[j][2] = a.z; wv[j][3] = a.w;
    wv[j][4] = b.x; wv[j][5] = b.y; wv[j][6] = b.z; wv[j][7] = b.w;
  }

  int tok0 = blockIdx.x * 64 + wave * 16;   // 256 blocks x 64 tokens
  for (int tt = 0; tt < 16; tt++) {
    int tok = tok0 + tt;
    const float* xr = x + (size_t)tok * DM;
    float xv[8];
#pragma unroll
    for (int j = 0; j < 8; j++) xv[j] = xr[j * 64 + lane];   // coalesced 256B/iter
    float acc[NE];
#pragma unroll
    for (int e = 0; e < NE; e++) acc[e] = 0.f;
#pragma unroll
    for (int j = 0; j < 8; j++)
#pragma unroll
      for (int e = 0; e < NE; e++) acc[e] += xv[j] * wv[j][e];
#pragma unroll
    for (int e = 0; e < NE; e++) {
#pragma unroll
      for (int off = 32; off > 0; off >>= 1) acc[e] += __shfl_xor(acc[e], off, 64);
    }
    if (lane == 0) {
      float mx = acc[0];
      for (int e = 1; e < NE; e++) mx = fmaxf(mx, acc[e]);
      float p[NE], s = 0.f;
      for (int e = 0; e < NE; e++) { p[e] = __expf(acc[e] - mx); s += p[e]; }
      float inv = 1.f / s;
      int e0 = 0; float v0 = p[0];
      for (int e = 1; e < NE; e++) if (p[e] > v0) { v0 = p[e]; e0 = e; }  // strict > = top_k tiebreak
      int e1 = -1; float v1 = -1.f;
      for (int e = 0; e < NE; e++) if (e != e0 && p[e] > v1) { v1 = p[e]; e1 = e; }
      tk_e[tok * 2]     = e0; tk_w[tok * 2]     = v0 * inv;
      tk_e[tok * 2 + 1] = e1; tk_w[tok * 2 + 1] = v1 * inv;
      atomicAdd(&hist[e0], 1);    // LDS atomic
      atomicAdd(&hist[e1], 1);
    }
  }
  __syncthreads();
  if (tid < NE) atomicAdd(&counts[tid], hist[tid]);   // 8 global atomics / block
}

// ---------------- prefix sums + tile map (single thread; E=8, <=263 tiles) ----------------
__global__ void k_setup(const int* __restrict__ counts, int* __restrict__ offsets,
                        int* __restrict__ tile_e, int* __restrict__ tile_r0, int* __restrict__ ntiles) {
  if (threadIdx.x != 0 || blockIdx.x != 0) return;
  int off = 0;
  for (int e = 0; e < NE; e++) { offsets[e] = off; off += counts[e]; }
  offsets[NE] = off;  // == NPAIR
  int nt = 0;
  for (int e = 0; e < NE; e++)
    for (int r = offsets[e]; r < offsets[e + 1]; r += BM) { tile_e[nt] = e; tile_r0[nt] = r; nt++; }
  *ntiles = nt;
}

// ------- build compact slot lists: LDS sub-histogram + ranged reservation (8 atomics/block) -------
__global__ __launch_bounds__(256) void k_build(const int* __restrict__ tk_e, const float* __restrict__ tk_w,
                                               const int* __restrict__ offsets, int* __restrict__ cursors,
                                               int* __restrict__ tok_of, float* __restrict__ w_of) {
  __shared__ int lcnt[NE], lbase[NE];
  int tid = threadIdx.x;
  int i = blockIdx.x * 256 + tid;   // pair index
  if (tid < NE) lcnt[tid] = 0;
  __syncthreads();
  int e = tk_e[i];
  int local = atomicAdd(&lcnt[e], 1);          // LDS atomic -> rank within block
  __syncthreads();
  if (tid < NE) lbase[tid] = atomicAdd(&cursors[tid], lcnt[tid]);  // reserve range
  __syncthreads();
  int slot = offsets[e] + lbase[e] + local;
  tok_of[slot] = i >> 1;
  w_of[slot] = tk_w[i];
}

// ---------------- GEMM1: h[slot][DFF] = relu(x[tok] @ W1[e] + b1[e])  (bf16, 128x128x64) ----------------
__global__ __launch_bounds__(256) void k_gemm1(
    const uint16_t* __restrict__ xb, const uint16_t* __restrict__ w1t,
    const float* __restrict__ b1,
    const int* __restrict__ tok_of, const int* __restrict__ offsets,
    const int* __restrict__ tile_e, const int* __restrict__ tile_r0,
    const int* __restrict__ ntiles, uint16_t* __restrict__ h) {
  __shared__ uint16_t smem[16384];          // sA 16KB | sB 16KB; reused for epilogue repack
  int t = blockIdx.x;
  if (t >= *ntiles) return;
  int e = tile_e[t], row0 = tile_r0[t], end = offsets[e + 1];
  int n0 = blockIdx.y * BN;
  int tid = threadIdx.x, lane = tid & 63, wave = tid >> 6;
  int wr = (wave >> 1) * 64, wc = (wave & 1) * 64;
  uint16_t* sA = smem;
  uint16_t* sB = smem + 8192;

  size_t abase[4], bbofs[4];
#pragma unroll
  for (int it = 0; it < 4; it++) {
    int chunk = it * 256 + tid;             // 1024 chunks of 8 bf16 = [128 rows][8 colchunks]
    int row = chunk >> 3, cc = chunk & 7;
    int slot = row0 + row; if (slot >= end) slot = row0;      // clamp: safe read, masked at store
    abase[it] = (size_t)tok_of[slot] * DM + (size_t)cc * 8;
    bbofs[it] = (size_t)row * DM + (size_t)cc * 8;
  }
  const uint16_t* bb = w1t + (size_t)e * DFF * DM + (size_t)n0 * DM;

  f32x4 acc[4][4];
#pragma unroll
  for (int r = 0; r < 4; r++)
#pragma unroll
    for (int c = 0; c < 4; c++)
#pragma unroll
      for (int i = 0; i < 4; i++) acc[r][c][i] = 0.f;

  for (int k0 = 0; k0 < DM; k0 += BK) {
#pragma unroll
    for (int it = 0; it < 4; it++)
      g2l16(xb + abase[it] + k0, sA + (size_t)(it * 256 + wave * 64) * 8);
#pragma unroll
    for (int it = 0; it < 4; it++)
      g2l16(bb + bbofs[it] + k0, sB + (size_t)(it * 256 + wave * 64) * 8);
    __syncthreads();
#pragma unroll
    for (int ks = 0; ks < BK; ks += 32) {
      int kk = ks + (lane >> 4) * 8;
      s16x8 af[4], bf[4];
#pragma unroll
      for (int r = 0; r < 4; r++) af[r] = *(const s16x8*)(sA + (wr + r * 16 + (lane & 15)) * BK + kk);
#pragma unroll
      for (int c = 0; c < 4; c++) bf[c] = *(const s16x8*)(sB + (wc + c * 16 + (lane & 15)) * BK + kk);
#pragma unroll
      for (int r = 0; r < 4; r++)
#pragma unroll
        for (int c = 0; c < 4; c++)
          acc[r][c] = __builtin_amdgcn_mfma_f32_16x16x32_bf16(af[r], bf[c], acc[r][c], 0, 0, 0);
    }
    __syncthreads();
  }

  // epilogue: bias+relu -> bf16 via LDS repack -> coalesced 16B stores
  float bv[4];
#pragma unroll
  for (int c = 0; c < 4; c++) bv[c] = b1[(size_t)e * DFF + n0 + wc + c * 16 + (lane & 15)];
  uint16_t* myreg = smem + wave * 4096;     // per-wave 64x64 bf16 region
#pragma unroll
  for (int r = 0; r < 4; r++)
#pragma unroll
    for (int c = 0; c < 4; c++)
#pragma unroll
      for (int i = 0; i < 4; i++) {
        int row = r * 16 + (lane >> 4) * 4 + i;           // C/D layout: col=lane&15, row=quad*4+reg
        int col = c * 16 + (lane & 15);
        float v = fmaxf(acc[r][c][i] + bv[c], 0.f);
        myreg[row * 64 + col] = f2b(v);
      }
  __syncthreads();
#pragma unroll
  for (int it = 0; it < 8; it++) {
    int chunk = it * 256 + tid;             // 2048 chunks of 8 bf16 over the 128x128 tile
    int row = chunk >> 4, cc = chunk & 15;
    int slot = row0 + row;
    if (slot < end) {
      int wv = (row >> 6) * 2 + (cc >> 3);
      const uint16_t* src = smem + wv * 4096 + (row & 63) * 64 + (cc & 7) * 8;
      *(s16x8*)(h + (size_t)slot * DFF + n0 + cc * 8) = *(const s16x8*)src;
    }
  }
}

// ---------------- GEMM2: out[tok] += w * (h[slot] @ W2[e] + b2[e]) ----------------
__global__ __launch_bounds__(256) void k_gemm2(
    const uint16_t* __restrict__ h, const uint16_t* __restrict__ w2t,
    const float* __restrict__ b2,
    const int* __restrict__ tok_of, const float* __restrict__ w_of,
    const int* __restrict__ offsets,
    const int* __restrict__ tile_e, const int* __restrict__ tile_r0,
    const int* __restrict__ ntiles, float* __restrict__ out) {
  __shared__ uint16_t smem[16384];
  int t = blockIdx.x;
  if (t >= *ntiles) return;
  int e = tile_e[t], row0 = tile_r0[t], end = offsets[e + 1];
  int n0 = blockIdx.y * BN;
  int tid = threadIdx.x, lane = tid & 63, wave = tid >> 6;
  int wr = (wave >> 1) * 64, wc = (wave & 1) * 64;
  uint16_t* sA = smem;
  uint16_t* sB = smem + 8192;

  size_t abase[4], bbofs[4];
#pragma unroll
  for (int it = 0; it < 4; it++) {
    int chunk = it * 256 + tid;
    int row = chunk >> 3, cc = chunk & 7;
    int slot = row0 + row; if (slot >= end) slot = row0;
    abase[it] = (size_t)slot * DFF + (size_t)cc * 8;
    bbofs[it] = (size_t)row * DFF + (size_t)cc * 8;
  }
  const uint16_t* bb = w2t + (size_t)e * DM * DFF + (size_t)n0 * DFF;

  f32x4 acc[4][4];
#pragma unroll
  for (int r = 0; r < 4; r++)
#pragma unroll
    for (int c = 0; c < 4; c++)
#pragma unroll
      for (int i = 0; i < 4; i++) acc[r][c][i] = 0.f;

  for (int k0 = 0; k0 < DFF; k0 += BK) {
#pragma unroll
    for (int it = 0; it < 4; it++)
      g2l16(h + abase[it] + k0, sA + (size_t)(it * 256 + wave * 64) * 8);
#pragma unroll
    for (int it = 0; it < 4; it++)
      g2l16(bb + bbofs[it] + k0, sB + (size_t)(it * 256 + wave * 64) * 8);
    __syncthreads();
#pragma unroll
    for (int ks = 0; ks < BK; ks += 32) {
      int kk = ks + (lane >> 4) * 8;
      s16x8 af[4], bf[4];
#pragma unroll
      for (int r = 0; r < 4; r++) af[r] = *(const s16x8*)(sA + (wr + r * 16 + (lane & 15)) * BK + kk);
#pragma unroll
      for (int c = 0; c < 4; c++) bf[c] = *(const s16x8*)(sB + (wc + c * 16 + (lane & 15)) * BK + kk);
#pragma unroll
      for (int r = 0; r < 4; r++)
#pragma unroll
        for (int c = 0; c < 4; c++)
          acc[r][c] = __builtin_amdgcn_mfma_f32_16x16x32_bf16(af[r], bf[c], acc[r][c], 0, 0, 0);
    }
    __syncthreads();
  }

  float bv[4];
#pragma unroll
  for (int c = 0; c < 4; c++) bv[c] = b2[(size_t)e * DM + n0 + wc + c * 16 + (lane & 15)];
#pragma unroll
  for (int r = 0; r < 4; r++)
#pragma unroll
    for (int i = 0; i < 4; i++) {
      int rowg = wr + r * 16 + (lane >> 4) * 4 + i;
      int slot = row0 + rowg;
      if (slot < end) {
        int tok = tok_of[slot];
        float wgt = w_of[slot];
        float* orow = out + (size_t)tok * DM + n0 + wc + (lane & 15);
#pragma unroll
        for (int c = 0; c < 4; c++)
          atomicAdd(orow + c * 16, wgt * (acc[r][c][i] + bv[c]));
      }
    }
}

extern "C" void kernel_launch(void* const* d_in, const int* in_sizes, int n_in,
                              void* d_out, int out_size, void* d_ws, size_t ws_size,
                              hipStream_t stream) {
  const float* x  = (const float*)d_in[0];
  const float* wg = (const float*)d_in[1];
  const float* w1 = (const float*)d_in[2];
  const float* b1 = (const float*)d_in[3];
  const float* w2 = (const float*)d_in[4];
  const float* b2 = (const float*)d_in[5];
  float* out = (float*)d_out;

  // workspace layout (~186 MB)
  char* ws = (char*)d_ws;
  uint16_t* xb   = (uint16_t*)ws;                                  // 16 MB
  uint16_t* w1t  = (uint16_t*)(ws + 16777216);                     // 16 MB  [E][DFF][DM]
  uint16_t* w2t  = (uint16_t*)(ws + 2 * 16777216);                 // 16 MB  [E][DM][DFF]
  uint16_t* hbuf = (uint16_t*)(ws + 3 * 16777216);                 // 128 MB [NPAIR][DFF]
  int* ctrl = (int*)(ws + 3 * 16777216 + 134217728);
  int*   counts  = ctrl;                 // 8
  int*   cursors = ctrl + 8;             // 8
  int*   offsets = ctrl + 16;            // 9
  int*   ntiles  = ctrl + 25;            // 1
  int*   tile_e  = ctrl + 32;            // 264
  int*   tile_r0 = ctrl + 296;           // 264
  int*   tk_e    = ctrl + 560;           // 32768
  float* tk_w    = (float*)(ctrl + 560 + 32768);
  int*   tok_of  = ctrl + 560 + 2 * 32768;
  float* w_of    = (float*)(ctrl + 560 + 3 * 32768);

  hipMemsetAsync(d_out, 0, (size_t)out_size * sizeof(float), stream);  // atomics accumulate into zeros
  hipMemsetAsync(counts, 0, 16 * sizeof(int), stream);                 // counts + cursors

  k_cvt<<<4096, 256, 0, stream>>>(x, xb, (BTOK * DM) / 8);
  k_tr<<<dim3(DFF / 32, DM / 32, NE), dim3(32, 8), 0, stream>>>(w1, w1t, DM, DFF);
  k_tr<<<dim3(DM / 32, DFF / 32, NE), dim3(32, 8), 0, stream>>>(w2, w2t, DFF, DM);
  k_route<<<BTOK / 64, 256, 0, stream>>>(x, wg, counts, tk_e, tk_w);
  k_setup<<<1, 64, 0, stream>>>(counts, offsets, tile_e, tile_r0, ntiles);
  k_build<<<NPAIR / 256, 256, 0, stream>>>(tk_e, tk_w, offsets, cursors, tok_of, w_of);
  k_gemm1<<<dim3(MAXTILES, DFF / BN), 256, 0, stream>>>(xb, w1t, b1, tok_of, offsets,
                                                        tile_e, tile_r0, ntiles, hbuf);
  k_gemm2<<<dim3(MAXTILES, DM / BN), 256, 0, stream>>>(hbuf, w2t, b2, tok_of, w_of, offsets,
                                                       tile_e, tile_r0, ntiles, out);
}

// Round 3
// 459.266 us; speedup vs baseline: 2.1698x; 1.0738x over previous
//
#include <hip/hip_runtime.h>
#include <stdint.h>

#define BTOK 16384
#define DM   512
#define DFF  2048
#define NE   8
#define NPAIR (BTOK*2)
#define BM 128
#define BN 128
#define BK 64
#define MAXTILES 264

typedef short s16x8 __attribute__((ext_vector_type(8)));   // 8 bf16 in 4 VGPRs
typedef float f32x4 __attribute__((ext_vector_type(4)));

// fp32 -> bf16 RNE (inputs finite)
__device__ __forceinline__ uint16_t f2b(float f) {
  uint32_t u = __float_as_uint(f);
  u += 0x7fff + ((u >> 16) & 1);
  return (uint16_t)(u >> 16);
}

// async global->LDS, 16B per lane; lds ptr must be wave-uniform base (HW adds lane*16)
__device__ __forceinline__ void g2l16(const void* gp, void* lp) {
  __builtin_amdgcn_global_load_lds(
      (__attribute__((address_space(1))) void*)(void*)gp,
      (__attribute__((address_space(3))) void*)lp, 16, 0, 0);
}

// ---------------- fp32 -> bf16 convert (8 elems/thread) ----------------
__global__ void k_cvt(const float* __restrict__ in, uint16_t* __restrict__ out, int n8) {
  int i = blockIdx.x * 256 + threadIdx.x;
  if (i >= n8) return;
  const float4* p = (const float4*)in + (size_t)i * 2;
  float4 a = p[0], b = p[1];
  uint16_t v[8] = {f2b(a.x), f2b(a.y), f2b(a.z), f2b(a.w),
                   f2b(b.x), f2b(b.y), f2b(b.z), f2b(b.w)};
  *(s16x8*)(out + (size_t)i * 8) = *(s16x8*)v;
}

// ---------- per-expert transpose+convert: in [E][R][C] fp32 -> out [E][C][R] bf16 ----------
__global__ void k_tr(const float* __restrict__ in, uint16_t* __restrict__ out, int R, int C) {
  __shared__ float t[32][33];
  int e = blockIdx.z;
  const float* src = in + (size_t)e * R * C;
  uint16_t* dst = out + (size_t)e * R * C;
  int c0 = blockIdx.x * 32, r0 = blockIdx.y * 32;
  int tx = threadIdx.x, ty = threadIdx.y;
#pragma unroll
  for (int j = 0; j < 4; j++)
    t[ty + j * 8][tx] = src[(size_t)(r0 + ty + j * 8) * C + c0 + tx];
  __syncthreads();
#pragma unroll
  for (int j = 0; j < 4; j++)
    dst[(size_t)(c0 + ty + j * 8) * R + r0 + tx] = f2b(t[tx][ty + j * 8]);
}

// ---- gate: wave-per-token x16, wg in registers, LDS histogram, 8 global atomics/block ----
__global__ __launch_bounds__(256) void k_route(const float* __restrict__ x,
                                               const float* __restrict__ wg,
                                               int* __restrict__ counts,
                                               int* __restrict__ tk_e, float* __restrict__ tk_w) {
  __shared__ int hist[NE];
  int tid = threadIdx.x, lane = tid & 63, wave = tid >> 6;
  if (tid < NE) hist[tid] = 0;
  __syncthreads();

  float wv[8][8];
#pragma unroll
  for (int j = 0; j < 8; j++) {
    const float4* wr = (const float4*)(wg + (size_t)(j * 64 + lane) * NE);
    float4 a = wr[0], b = wr[1];
    wv[j][0] = a.x; wv[j][1] = a.y; wv[j][2] = a.z; wv[j][3] = a.w;
    wv[j][4] = b.x; wv[j][5] = b.y; wv[j][6] = b.z; wv[j][7] = b.w;
  }

  int tok0 = blockIdx.x * 64 + wave * 16;
  for (int tt = 0; tt < 16; tt++) {
    int tok = tok0 + tt;
    const float* xr = x + (size_t)tok * DM;
    float xv[8];
#pragma unroll
    for (int j = 0; j < 8; j++) xv[j] = xr[j * 64 + lane];
    float acc[NE];
#pragma unroll
    for (int e = 0; e < NE; e++) acc[e] = 0.f;
#pragma unroll
    for (int j = 0; j < 8; j++)
#pragma unroll
      for (int e = 0; e < NE; e++) acc[e] += xv[j] * wv[j][e];
#pragma unroll
    for (int e = 0; e < NE; e++) {
#pragma unroll
      for (int off = 32; off > 0; off >>= 1) acc[e] += __shfl_xor(acc[e], off, 64);
    }
    if (lane == 0) {
      float mx = acc[0];
      for (int e = 1; e < NE; e++) mx = fmaxf(mx, acc[e]);
      float p[NE], s = 0.f;
      for (int e = 0; e < NE; e++) { p[e] = __expf(acc[e] - mx); s += p[e]; }
      float inv = 1.f / s;
      int e0 = 0; float v0 = p[0];
      for (int e = 1; e < NE; e++) if (p[e] > v0) { v0 = p[e]; e0 = e; }  // strict > = top_k tiebreak
      int e1 = -1; float v1 = -1.f;
      for (int e = 0; e < NE; e++) if (e != e0 && p[e] > v1) { v1 = p[e]; e1 = e; }
      tk_e[tok * 2]     = e0; tk_w[tok * 2]     = v0 * inv;
      tk_e[tok * 2 + 1] = e1; tk_w[tok * 2 + 1] = v1 * inv;
      atomicAdd(&hist[e0], 1);
      atomicAdd(&hist[e1], 1);
    }
  }
  __syncthreads();
  if (tid < NE) atomicAdd(&counts[tid], hist[tid]);
}

// ---------------- prefix sums + tile map ----------------
__global__ void k_setup(const int* __restrict__ counts, int* __restrict__ offsets,
                        int* __restrict__ tile_e, int* __restrict__ tile_r0, int* __restrict__ ntiles) {
  if (threadIdx.x != 0 || blockIdx.x != 0) return;
  int off = 0;
  for (int e = 0; e < NE; e++) { offsets[e] = off; off += counts[e]; }
  offsets[NE] = off;
  int nt = 0;
  for (int e = 0; e < NE; e++)
    for (int r = offsets[e]; r < offsets[e + 1]; r += BM) { tile_e[nt] = e; tile_r0[nt] = r; nt++; }
  *ntiles = nt;
}

// ------- build compact slot lists: LDS sub-histogram + ranged reservation -------
__global__ __launch_bounds__(256) void k_build(const int* __restrict__ tk_e, const float* __restrict__ tk_w,
                                               const int* __restrict__ offsets, int* __restrict__ cursors,
                                               int* __restrict__ tok_of, float* __restrict__ w_of) {
  __shared__ int lcnt[NE], lbase[NE];
  int tid = threadIdx.x;
  int i = blockIdx.x * 256 + tid;
  if (tid < NE) lcnt[tid] = 0;
  __syncthreads();
  int e = tk_e[i];
  int local = atomicAdd(&lcnt[e], 1);
  __syncthreads();
  if (tid < NE) lbase[tid] = atomicAdd(&cursors[tid], lcnt[tid]);
  __syncthreads();
  int slot = offsets[e] + lbase[e] + local;
  tok_of[slot] = i >> 1;
  w_of[slot] = tk_w[i];
}

// ---------------- GEMM1: h[slot][DFF] = relu(x[tok] @ W1[e] + b1[e]) ----------------
// LDS layout: row-major [128][BK] with XOR column swizzle slot = chunk ^ (row&7)
// grid: 1-D, id -> (tile, n0) such that all 16 n-tiles of a row-tile share id%8 (same XCD)
__global__ __launch_bounds__(256) void k_gemm1(
    const uint16_t* __restrict__ xb, const uint16_t* __restrict__ w1t,
    const float* __restrict__ b1,
    const int* __restrict__ tok_of, const int* __restrict__ offsets,
    const int* __restrict__ tile_e, const int* __restrict__ tile_r0,
    const int* __restrict__ ntiles, uint16_t* __restrict__ h) {
  __shared__ uint16_t smem[16384];
  int id = blockIdx.x;
  int t = ((id >> 7) << 3) | (id & 7);      // row-tile: ids t, t+8.. (mod pattern) same XCD
  int n0 = ((id >> 3) & 15) * BN;
  if (t >= *ntiles) return;
  int e = tile_e[t], row0 = tile_r0[t], end = offsets[e + 1];
  int tid = threadIdx.x, lane = tid & 63, wave = tid >> 6;
  int wr = (wave >> 1) * 64, wc = (wave & 1) * 64;
  int sw = lane & 7;                        // fragment-read XOR key
  uint16_t* sA = smem;
  uint16_t* sB = smem + 8192;

  size_t abase[4], bbofs[4];
#pragma unroll
  for (int it = 0; it < 4; it++) {
    int chunk = it * 256 + tid;             // LDS slot index (row-major, contiguous)
    int row = chunk >> 3, s = chunk & 7;
    int c = s ^ (row & 7);                  // which global chunk lands in this slot
    int slot = row0 + row; if (slot >= end) slot = row0;
    abase[it] = (size_t)tok_of[slot] * DM + (size_t)c * 8;
    bbofs[it] = (size_t)row * DM + (size_t)c * 8;
  }
  const uint16_t* bb = w1t + (size_t)e * DFF * DM + (size_t)n0 * DM;

  f32x4 acc[4][4];
#pragma unroll
  for (int r = 0; r < 4; r++)
#pragma unroll
    for (int c = 0; c < 4; c++)
#pragma unroll
      for (int i = 0; i < 4; i++) acc[r][c][i] = 0.f;

  for (int k0 = 0; k0 < DM; k0 += BK) {
#pragma unroll
    for (int it = 0; it < 4; it++)
      g2l16(xb + abase[it] + k0, sA + (size_t)(it * 256 + wave * 64) * 8);
#pragma unroll
    for (int it = 0; it < 4; it++)
      g2l16(bb + bbofs[it] + k0, sB + (size_t)(it * 256 + wave * 64) * 8);
    __syncthreads();
#pragma unroll
    for (int ks = 0; ks < BK; ks += 32) {
      int cb = (ks >> 3) + (lane >> 4);     // chunk index within row
      int co = (cb ^ sw) << 3;              // swizzled element offset
      s16x8 af[4], bf[4];
#pragma unroll
      for (int r = 0; r < 4; r++) af[r] = *(const s16x8*)(sA + (wr + r * 16 + (lane & 15)) * BK + co);
#pragma unroll
      for (int c = 0; c < 4; c++) bf[c] = *(const s16x8*)(sB + (wc + c * 16 + (lane & 15)) * BK + co);
#pragma unroll
      for (int r = 0; r < 4; r++)
#pragma unroll
        for (int c = 0; c < 4; c++)
          acc[r][c] = __builtin_amdgcn_mfma_f32_16x16x32_bf16(af[r], bf[c], acc[r][c], 0, 0, 0);
    }
    __syncthreads();
  }

  // epilogue: bias+relu -> bf16 via LDS repack -> coalesced 16B stores
  float bv[4];
#pragma unroll
  for (int c = 0; c < 4; c++) bv[c] = b1[(size_t)e * DFF + n0 + wc + c * 16 + (lane & 15)];
  uint16_t* myreg = smem + wave * 4096;
#pragma unroll
  for (int r = 0; r < 4; r++)
#pragma unroll
    for (int c = 0; c < 4; c++)
#pragma unroll
      for (int i = 0; i < 4; i++) {
        int row = r * 16 + (lane >> 4) * 4 + i;           // C/D: col=lane&15, row=quad*4+reg
        int col = c * 16 + (lane & 15);
        float v = fmaxf(acc[r][c][i] + bv[c], 0.f);
        myreg[row * 64 + col] = f2b(v);
      }
  __syncthreads();
#pragma unroll
  for (int it = 0; it < 8; it++) {
    int chunk = it * 256 + tid;
    int row = chunk >> 4, cc = chunk & 15;
    int slot = row0 + row;
    if (slot < end) {
      int wv = (row >> 6) * 2 + (cc >> 3);
      const uint16_t* src = smem + wv * 4096 + (row & 63) * 64 + (cc & 7) * 8;
      *(s16x8*)(h + (size_t)slot * DFF + n0 + cc * 8) = *(const s16x8*)src;
    }
  }
}

// ---------------- GEMM2: out[tok] += w * (h[slot] @ W2[e] + b2[e]) ----------------
// grid: 1-D, id -> (tile, n0) with the 4 n-tiles of a row-tile at ids ≡ (mod 8) -> same XCD L2
__global__ __launch_bounds__(256) void k_gemm2(
    const uint16_t* __restrict__ h, const uint16_t* __restrict__ w2t,
    const float* __restrict__ b2,
    const int* __restrict__ tok_of, const float* __restrict__ w_of,
    const int* __restrict__ offsets,
    const int* __restrict__ tile_e, const int* __restrict__ tile_r0,
    const int* __restrict__ ntiles, float* __restrict__ out) {
  __shared__ uint16_t smem[16384];
  int id = blockIdx.x;
  int t = ((id >> 5) << 3) | (id & 7);
  int n0 = ((id >> 3) & 3) * BN;
  if (t >= *ntiles) return;
  int e = tile_e[t], row0 = tile_r0[t], end = offsets[e + 1];
  int tid = threadIdx.x, lane = tid & 63, wave = tid >> 6;
  int wr = (wave >> 1) * 64, wc = (wave & 1) * 64;
  int sw = lane & 7;
  uint16_t* sA = smem;
  uint16_t* sB = smem + 8192;

  size_t abase[4], bbofs[4];
#pragma unroll
  for (int it = 0; it < 4; it++) {
    int chunk = it * 256 + tid;
    int row = chunk >> 3, s = chunk & 7;
    int c = s ^ (row & 7);
    int slot = row0 + row; if (slot >= end) slot = row0;
    abase[it] = (size_t)slot * DFF + (size_t)c * 8;
    bbofs[it] = (size_t)row * DFF + (size_t)c * 8;
  }
  const uint16_t* bb = w2t + (size_t)e * DM * DFF + (size_t)n0 * DFF;

  f32x4 acc[4][4];
#pragma unroll
  for (int r = 0; r < 4; r++)
#pragma unroll
    for (int c = 0; c < 4; c++)
#pragma unroll
      for (int i = 0; i < 4; i++) acc[r][c][i] = 0.f;

  for (int k0 = 0; k0 < DFF; k0 += BK) {
#pragma unroll
    for (int it = 0; it < 4; it++)
      g2l16(h + abase[it] + k0, sA + (size_t)(it * 256 + wave * 64) * 8);
#pragma unroll
    for (int it = 0; it < 4; it++)
      g2l16(bb + bbofs[it] + k0, sB + (size_t)(it * 256 + wave * 64) * 8);
    __syncthreads();
#pragma unroll
    for (int ks = 0; ks < BK; ks += 32) {
      int cb = (ks >> 3) + (lane >> 4);
      int co = (cb ^ sw) << 3;
      s16x8 af[4], bf[4];
#pragma unroll
      for (int r = 0; r < 4; r++) af[r] = *(const s16x8*)(sA + (wr + r * 16 + (lane & 15)) * BK + co);
#pragma unroll
      for (int c = 0; c < 4; c++) bf[c] = *(const s16x8*)(sB + (wc + c * 16 + (lane & 15)) * BK + co);
#pragma unroll
      for (int r = 0; r < 4; r++)
#pragma unroll
        for (int c = 0; c < 4; c++)
          acc[r][c] = __builtin_amdgcn_mfma_f32_16x16x32_bf16(af[r], bf[c], acc[r][c], 0, 0, 0);
    }
    __syncthreads();
  }

  float bv[4];
#pragma unroll
  for (int c = 0; c < 4; c++) bv[c] = b2[(size_t)e * DM + n0 + wc + c * 16 + (lane & 15)];
#pragma unroll
  for (int r = 0; r < 4; r++)
#pragma unroll
    for (int i = 0; i < 4; i++) {
      int rowg = wr + r * 16 + (lane >> 4) * 4 + i;
      int slot = row0 + rowg;
      if (slot < end) {
        int tok = tok_of[slot];
        float wgt = w_of[slot];
        float* orow = out + (size_t)tok * DM + n0 + wc + (lane & 15);
#pragma unroll
        for (int c = 0; c < 4; c++)
          atomicAdd(orow + c * 16, wgt * (acc[r][c][i] + bv[c]));
      }
    }
}

extern "C" void kernel_launch(void* const* d_in, const int* in_sizes, int n_in,
                              void* d_out, int out_size, void* d_ws, size_t ws_size,
                              hipStream_t stream) {
  const float* x  = (const float*)d_in[0];
  const float* wg = (const float*)d_in[1];
  const float* w1 = (const float*)d_in[2];
  const float* b1 = (const float*)d_in[3];
  const float* w2 = (const float*)d_in[4];
  const float* b2 = (const float*)d_in[5];
  float* out = (float*)d_out;

  char* ws = (char*)d_ws;
  uint16_t* xb   = (uint16_t*)ws;                                  // 16 MB
  uint16_t* w1t  = (uint16_t*)(ws + 16777216);                     // 16 MB  [E][DFF][DM]
  uint16_t* w2t  = (uint16_t*)(ws + 2 * 16777216);                 // 16 MB  [E][DM][DFF]
  uint16_t* hbuf = (uint16_t*)(ws + 3 * 16777216);                 // 128 MB [NPAIR][DFF]
  int* ctrl = (int*)(ws + 3 * 16777216 + 134217728);
  int*   counts  = ctrl;
  int*   cursors = ctrl + 8;
  int*   offsets = ctrl + 16;
  int*   ntiles  = ctrl + 25;
  int*   tile_e  = ctrl + 32;
  int*   tile_r0 = ctrl + 296;
  int*   tk_e    = ctrl + 560;
  float* tk_w    = (float*)(ctrl + 560 + 32768);
  int*   tok_of  = ctrl + 560 + 2 * 32768;
  float* w_of    = (float*)(ctrl + 560 + 3 * 32768);

  hipMemsetAsync(d_out, 0, (size_t)out_size * sizeof(float), stream);
  hipMemsetAsync(counts, 0, 16 * sizeof(int), stream);

  k_cvt<<<4096, 256, 0, stream>>>(x, xb, (BTOK * DM) / 8);
  k_tr<<<dim3(DFF / 32, DM / 32, NE), dim3(32, 8), 0, stream>>>(w1, w1t, DM, DFF);
  k_tr<<<dim3(DM / 32, DFF / 32, NE), dim3(32, 8), 0, stream>>>(w2, w2t, DFF, DM);
  k_route<<<BTOK / 64, 256, 0, stream>>>(x, wg, counts, tk_e, tk_w);
  k_setup<<<1, 64, 0, stream>>>(counts, offsets, tile_e, tile_r0, ntiles);
  k_build<<<NPAIR / 256, 256, 0, stream>>>(tk_e, tk_w, offsets, cursors, tok_of, w_of);
  k_gemm1<<<MAXTILES * (DFF / BN), 256, 0, stream>>>(xb, w1t, b1, tok_of, offsets,
                                                     tile_e, tile_r0, ntiles, hbuf);
  k_gemm2<<<MAXTILES * (DM / BN), 256, 0, stream>>>(hbuf, w2t, b2, tok_of, w_of, offsets,
                                                    tile_e, tile_r0, ntiles, out);
}

// Round 4
// 427.083 us; speedup vs baseline: 2.3333x; 1.0754x over previous
//
#include <hip/hip_runtime.h>
#include <stdint.h>

#define BTOK 16384
#define DM   512
#define DFF  2048
#define NE   8
#define NPAIR (BTOK*2)
#define BM 128
#define BN 128
#define BK 64
#define MAXTILES 264

typedef short s16x8 __attribute__((ext_vector_type(8)));   // 8 bf16 in 4 VGPRs
typedef float f32x4 __attribute__((ext_vector_type(4)));

// fp32 -> bf16 RNE (inputs finite)
__device__ __forceinline__ uint16_t f2b(float f) {
  uint32_t u = __float_as_uint(f);
  u += 0x7fff + ((u >> 16) & 1);
  return (uint16_t)(u >> 16);
}

// async global->LDS, 16B per lane; lds ptr must be wave-uniform base (HW adds lane*16)
__device__ __forceinline__ void g2l16(const void* gp, void* lp) {
  __builtin_amdgcn_global_load_lds(
      (__attribute__((address_space(1))) void*)(void*)gp,
      (__attribute__((address_space(3))) void*)lp, 16, 0, 0);
}

// ---------------- fp32 -> bf16 convert (8 elems/thread) ----------------
__global__ void k_cvt(const float* __restrict__ in, uint16_t* __restrict__ out, int n8) {
  int i = blockIdx.x * 256 + threadIdx.x;
  if (i >= n8) return;
  const float4* p = (const float4*)in + (size_t)i * 2;
  float4 a = p[0], b = p[1];
  uint16_t v[8] = {f2b(a.x), f2b(a.y), f2b(a.z), f2b(a.w),
                   f2b(b.x), f2b(b.y), f2b(b.z), f2b(b.w)};
  *(s16x8*)(out + (size_t)i * 8) = *(s16x8*)v;
}

// ---------- per-expert transpose+convert: in [E][R][C] fp32 -> out [E][C][R] bf16 ----------
__global__ void k_tr(const float* __restrict__ in, uint16_t* __restrict__ out, int R, int C) {
  __shared__ float t[32][33];
  int e = blockIdx.z;
  const float* src = in + (size_t)e * R * C;
  uint16_t* dst = out + (size_t)e * R * C;
  int c0 = blockIdx.x * 32, r0 = blockIdx.y * 32;
  int tx = threadIdx.x, ty = threadIdx.y;
#pragma unroll
  for (int j = 0; j < 4; j++)
    t[ty + j * 8][tx] = src[(size_t)(r0 + ty + j * 8) * C + c0 + tx];
  __syncthreads();
#pragma unroll
  for (int j = 0; j < 4; j++)
    dst[(size_t)(c0 + ty + j * 8) * R + r0 + tx] = f2b(t[tx][ty + j * 8]);
}

// ---- gate: wave-per-token x16, wg in registers, LDS histogram, 8 global atomics/block ----
__global__ __launch_bounds__(256) void k_route(const float* __restrict__ x,
                                               const float* __restrict__ wg,
                                               int* __restrict__ counts,
                                               int* __restrict__ tk_e, float* __restrict__ tk_w) {
  __shared__ int hist[NE];
  int tid = threadIdx.x, lane = tid & 63, wave = tid >> 6;
  if (tid < NE) hist[tid] = 0;
  __syncthreads();

  float wv[8][8];
#pragma unroll
  for (int j = 0; j < 8; j++) {
    const float4* wr = (const float4*)(wg + (size_t)(j * 64 + lane) * NE);
    float4 a = wr[0], b = wr[1];
    wv[j][0] = a.x; wv[j][1] = a.y; wv[j][2] = a.z; wv[j][3] = a.w;
    wv[j][4] = b.x; wv[j][5] = b.y; wv[j][6] = b.z; wv[j][7] = b.w;
  }

  int tok0 = blockIdx.x * 64 + wave * 16;
  for (int tt = 0; tt < 16; tt++) {
    int tok = tok0 + tt;
    const float* xr = x + (size_t)tok * DM;
    float xv[8];
#pragma unroll
    for (int j = 0; j < 8; j++) xv[j] = xr[j * 64 + lane];
    float acc[NE];
#pragma unroll
    for (int e = 0; e < NE; e++) acc[e] = 0.f;
#pragma unroll
    for (int j = 0; j < 8; j++)
#pragma unroll
      for (int e = 0; e < NE; e++) acc[e] += xv[j] * wv[j][e];
#pragma unroll
    for (int e = 0; e < NE; e++) {
#pragma unroll
      for (int off = 32; off > 0; off >>= 1) acc[e] += __shfl_xor(acc[e], off, 64);
    }
    if (lane == 0) {
      float mx = acc[0];
      for (int e = 1; e < NE; e++) mx = fmaxf(mx, acc[e]);
      float p[NE], s = 0.f;
      for (int e = 0; e < NE; e++) { p[e] = __expf(acc[e] - mx); s += p[e]; }
      float inv = 1.f / s;
      int e0 = 0; float v0 = p[0];
      for (int e = 1; e < NE; e++) if (p[e] > v0) { v0 = p[e]; e0 = e; }  // strict > = top_k tiebreak
      int e1 = -1; float v1 = -1.f;
      for (int e = 0; e < NE; e++) if (e != e0 && p[e] > v1) { v1 = p[e]; e1 = e; }
      tk_e[tok * 2]     = e0; tk_w[tok * 2]     = v0 * inv;
      tk_e[tok * 2 + 1] = e1; tk_w[tok * 2 + 1] = v1 * inv;
      atomicAdd(&hist[e0], 1);
      atomicAdd(&hist[e1], 1);
    }
  }
  __syncthreads();
  if (tid < NE) atomicAdd(&counts[tid], hist[tid]);
}

// ---------------- prefix sums + tile map ----------------
__global__ void k_setup(const int* __restrict__ counts, int* __restrict__ offsets,
                        int* __restrict__ tile_e, int* __restrict__ tile_r0, int* __restrict__ ntiles) {
  if (threadIdx.x != 0 || blockIdx.x != 0) return;
  int off = 0;
  for (int e = 0; e < NE; e++) { offsets[e] = off; off += counts[e]; }
  offsets[NE] = off;
  int nt = 0;
  for (int e = 0; e < NE; e++)
    for (int r = offsets[e]; r < offsets[e + 1]; r += BM) { tile_e[nt] = e; tile_r0[nt] = r; nt++; }
  *ntiles = nt;
}

// ------- build compact slot lists + inverse map: LDS sub-histogram + ranged reservation -------
__global__ __launch_bounds__(256) void k_build(const int* __restrict__ tk_e, const float* __restrict__ tk_w,
                                               const int* __restrict__ offsets, int* __restrict__ cursors,
                                               int* __restrict__ tok_of, float* __restrict__ w_of,
                                               int* __restrict__ inv) {
  __shared__ int lcnt[NE], lbase[NE];
  int tid = threadIdx.x;
  int i = blockIdx.x * 256 + tid;
  if (tid < NE) lcnt[tid] = 0;
  __syncthreads();
  int e = tk_e[i];
  int local = atomicAdd(&lcnt[e], 1);
  __syncthreads();
  if (tid < NE) lbase[tid] = atomicAdd(&cursors[tid], lcnt[tid]);
  __syncthreads();
  int slot = offsets[e] + lbase[e] + local;
  tok_of[slot] = i >> 1;
  w_of[slot] = tk_w[i];
  inv[i] = slot;
}

// ---------------- GEMM1: h[slot][DFF] = relu(x[tok] @ W1[e] + b1[e]) ----------------
// LDS: row-major [128][BK], XOR column swizzle slot = chunk ^ (row&7)
// grid: 1-D, all 16 n-tiles of a row-tile share id%8 (same XCD)
__global__ __launch_bounds__(256) void k_gemm1(
    const uint16_t* __restrict__ xb, const uint16_t* __restrict__ w1t,
    const float* __restrict__ b1,
    const int* __restrict__ tok_of, const int* __restrict__ offsets,
    const int* __restrict__ tile_e, const int* __restrict__ tile_r0,
    const int* __restrict__ ntiles, uint16_t* __restrict__ h) {
  __shared__ uint16_t smem[16384];
  int id = blockIdx.x;
  int t = ((id >> 7) << 3) | (id & 7);
  int n0 = ((id >> 3) & 15) * BN;
  if (t >= *ntiles) return;
  int e = tile_e[t], row0 = tile_r0[t], end = offsets[e + 1];
  int tid = threadIdx.x, lane = tid & 63, wave = tid >> 6;
  int wr = (wave >> 1) * 64, wc = (wave & 1) * 64;
  int sw = lane & 7;
  uint16_t* sA = smem;
  uint16_t* sB = smem + 8192;

  size_t abase[4], bbofs[4];
#pragma unroll
  for (int it = 0; it < 4; it++) {
    int chunk = it * 256 + tid;
    int row = chunk >> 3, s = chunk & 7;
    int c = s ^ (row & 7);
    int slot = row0 + row; if (slot >= end) slot = row0;
    abase[it] = (size_t)tok_of[slot] * DM + (size_t)c * 8;
    bbofs[it] = (size_t)row * DM + (size_t)c * 8;
  }
  const uint16_t* bb = w1t + (size_t)e * DFF * DM + (size_t)n0 * DM;

  f32x4 acc[4][4];
#pragma unroll
  for (int r = 0; r < 4; r++)
#pragma unroll
    for (int c = 0; c < 4; c++)
#pragma unroll
      for (int i = 0; i < 4; i++) acc[r][c][i] = 0.f;

  for (int k0 = 0; k0 < DM; k0 += BK) {
#pragma unroll
    for (int it = 0; it < 4; it++)
      g2l16(xb + abase[it] + k0, sA + (size_t)(it * 256 + wave * 64) * 8);
#pragma unroll
    for (int it = 0; it < 4; it++)
      g2l16(bb + bbofs[it] + k0, sB + (size_t)(it * 256 + wave * 64) * 8);
    __syncthreads();
#pragma unroll
    for (int ks = 0; ks < BK; ks += 32) {
      int cb = (ks >> 3) + (lane >> 4);
      int co = (cb ^ sw) << 3;
      s16x8 af[4], bf[4];
#pragma unroll
      for (int r = 0; r < 4; r++) af[r] = *(const s16x8*)(sA + (wr + r * 16 + (lane & 15)) * BK + co);
#pragma unroll
      for (int c = 0; c < 4; c++) bf[c] = *(const s16x8*)(sB + (wc + c * 16 + (lane & 15)) * BK + co);
#pragma unroll
      for (int r = 0; r < 4; r++)
#pragma unroll
        for (int c = 0; c < 4; c++)
          acc[r][c] = __builtin_amdgcn_mfma_f32_16x16x32_bf16(af[r], bf[c], acc[r][c], 0, 0, 0);
    }
    __syncthreads();
  }

  // epilogue: bias+relu -> bf16 via LDS repack -> coalesced 16B stores
  float bv[4];
#pragma unroll
  for (int c = 0; c < 4; c++) bv[c] = b1[(size_t)e * DFF + n0 + wc + c * 16 + (lane & 15)];
  uint16_t* myreg = smem + wave * 4096;
#pragma unroll
  for (int r = 0; r < 4; r++)
#pragma unroll
    for (int c = 0; c < 4; c++)
#pragma unroll
      for (int i = 0; i < 4; i++) {
        int row = r * 16 + (lane >> 4) * 4 + i;           // C/D: col=lane&15, row=quad*4+reg
        int col = c * 16 + (lane & 15);
        float v = fmaxf(acc[r][c][i] + bv[c], 0.f);
        myreg[row * 64 + col] = f2b(v);
      }
  __syncthreads();
#pragma unroll
  for (int it = 0; it < 8; it++) {
    int chunk = it * 256 + tid;
    int row = chunk >> 4, cc = chunk & 15;
    int slot = row0 + row;
    if (slot < end) {
      int wv = (row >> 6) * 2 + (cc >> 3);
      const uint16_t* src = smem + wv * 4096 + (row & 63) * 64 + (cc & 7) * 8;
      *(s16x8*)(h + (size_t)slot * DFF + n0 + cc * 8) = *(const s16x8*)src;
    }
  }
}

// ---------------- GEMM2: y[slot] = w_of[slot] * (h[slot] @ W2[e] + b2[e])  (NO atomics) ----------------
__global__ __launch_bounds__(256) void k_gemm2(
    const uint16_t* __restrict__ h, const uint16_t* __restrict__ w2t,
    const float* __restrict__ b2,
    const float* __restrict__ w_of,
    const int* __restrict__ offsets,
    const int* __restrict__ tile_e, const int* __restrict__ tile_r0,
    const int* __restrict__ ntiles,
    float* __restrict__ y32, uint16_t* __restrict__ y16, int use32) {
  __shared__ uint16_t smem[16384];
  int id = blockIdx.x;
  int t = ((id >> 5) << 3) | (id & 7);
  int n0 = ((id >> 3) & 3) * BN;
  if (t >= *ntiles) return;
  int e = tile_e[t], row0 = tile_r0[t], end = offsets[e + 1];
  int tid = threadIdx.x, lane = tid & 63, wave = tid >> 6;
  int wr = (wave >> 1) * 64, wc = (wave & 1) * 64;
  int sw = lane & 7;
  uint16_t* sA = smem;
  uint16_t* sB = smem + 8192;

  size_t abase[4], bbofs[4];
#pragma unroll
  for (int it = 0; it < 4; it++) {
    int chunk = it * 256 + tid;
    int row = chunk >> 3, s = chunk & 7;
    int c = s ^ (row & 7);
    int slot = row0 + row; if (slot >= end) slot = row0;
    abase[it] = (size_t)slot * DFF + (size_t)c * 8;
    bbofs[it] = (size_t)row * DFF + (size_t)c * 8;
  }
  const uint16_t* bb = w2t + (size_t)e * DM * DFF + (size_t)n0 * DFF;

  f32x4 acc[4][4];
#pragma unroll
  for (int r = 0; r < 4; r++)
#pragma unroll
    for (int c = 0; c < 4; c++)
#pragma unroll
      for (int i = 0; i < 4; i++) acc[r][c][i] = 0.f;

  for (int k0 = 0; k0 < DFF; k0 += BK) {
#pragma unroll
    for (int it = 0; it < 4; it++)
      g2l16(h + abase[it] + k0, sA + (size_t)(it * 256 + wave * 64) * 8);
#pragma unroll
    for (int it = 0; it < 4; it++)
      g2l16(bb + bbofs[it] + k0, sB + (size_t)(it * 256 + wave * 64) * 8);
    __syncthreads();
#pragma unroll
    for (int ks = 0; ks < BK; ks += 32) {
      int cb = (ks >> 3) + (lane >> 4);
      int co = (cb ^ sw) << 3;
      s16x8 af[4], bf[4];
#pragma unroll
      for (int r = 0; r < 4; r++) af[r] = *(const s16x8*)(sA + (wr + r * 16 + (lane & 15)) * BK + co);
#pragma unroll
      for (int c = 0; c < 4; c++) bf[c] = *(const s16x8*)(sB + (wc + c * 16 + (lane & 15)) * BK + co);
#pragma unroll
      for (int r = 0; r < 4; r++)
#pragma unroll
        for (int c = 0; c < 4; c++)
          acc[r][c] = __builtin_amdgcn_mfma_f32_16x16x32_bf16(af[r], bf[c], acc[r][c], 0, 0, 0);
    }
    __syncthreads();
  }

  float bv[4];
#pragma unroll
  for (int c = 0; c < 4; c++) bv[c] = b2[(size_t)e * DM + n0 + wc + c * 16 + (lane & 15)];
#pragma unroll
  for (int r = 0; r < 4; r++)
#pragma unroll
    for (int i = 0; i < 4; i++) {
      int rowg = wr + r * 16 + (lane >> 4) * 4 + i;
      int slot = row0 + rowg;
      if (slot < end) {
        float wgt = w_of[slot];
        size_t base = (size_t)slot * DM + n0 + wc + (lane & 15);
        if (use32) {
#pragma unroll
          for (int c = 0; c < 4; c++) y32[base + c * 16] = wgt * (acc[r][c][i] + bv[c]);
        } else {
#pragma unroll
          for (int c = 0; c < 4; c++) y16[base + c * 16] = f2b(wgt * (acc[r][c][i] + bv[c]));
        }
      }
    }
}

// ---------------- combine: out[tok] = y[slot0] + y[slot1] (weights pre-applied) ----------------
__global__ __launch_bounds__(256) void k_combine(const float* __restrict__ y32,
                                                 const uint16_t* __restrict__ y16, int use32,
                                                 const int* __restrict__ inv,
                                                 float* __restrict__ out) {
  int tid = threadIdx.x;
  int tok = blockIdx.x * 2 + (tid >> 7);
  int c4 = (tid & 127) * 4;                  // 128 threads x float4 = 512 cols
  int s0 = inv[tok * 2], s1 = inv[tok * 2 + 1];
  float4 o;
  if (use32) {
    const float4 a = *(const float4*)(y32 + (size_t)s0 * DM + c4);
    const float4 b = *(const float4*)(y32 + (size_t)s1 * DM + c4);
    o = make_float4(a.x + b.x, a.y + b.y, a.z + b.z, a.w + b.w);
  } else {
    const ushort4 a = *(const ushort4*)(y16 + (size_t)s0 * DM + c4);
    const ushort4 b = *(const ushort4*)(y16 + (size_t)s1 * DM + c4);
    o = make_float4(__uint_as_float((uint32_t)a.x << 16) + __uint_as_float((uint32_t)b.x << 16),
                    __uint_as_float((uint32_t)a.y << 16) + __uint_as_float((uint32_t)b.y << 16),
                    __uint_as_float((uint32_t)a.z << 16) + __uint_as_float((uint32_t)b.z << 16),
                    __uint_as_float((uint32_t)a.w << 16) + __uint_as_float((uint32_t)b.w << 16));
  }
  *(float4*)(out + (size_t)tok * DM + c4) = o;
}

extern "C" void kernel_launch(void* const* d_in, const int* in_sizes, int n_in,
                              void* d_out, int out_size, void* d_ws, size_t ws_size,
                              hipStream_t stream) {
  const float* x  = (const float*)d_in[0];
  const float* wg = (const float*)d_in[1];
  const float* w1 = (const float*)d_in[2];
  const float* b1 = (const float*)d_in[3];
  const float* w2 = (const float*)d_in[4];
  const float* b2 = (const float*)d_in[5];
  float* out = (float*)d_out;

  char* ws = (char*)d_ws;
  const size_t MB = 1024 * 1024;
  uint16_t* xb   = (uint16_t*)ws;                  // [0,16) MB
  uint16_t* w1t  = (uint16_t*)(ws + 16 * MB);      // [16,32) MB  [E][DFF][DM]
  uint16_t* w2t  = (uint16_t*)(ws + 32 * MB);      // [32,48) MB  [E][DM][DFF]
  uint16_t* hbuf = (uint16_t*)(ws + 48 * MB);      // [48,176) MB [NPAIR][DFF]
  int* ctrl = (int*)(ws + 176 * MB);               // [176,177) MB
  int*   counts  = ctrl;
  int*   cursors = ctrl + 8;
  int*   offsets = ctrl + 16;
  int*   ntiles  = ctrl + 25;
  int*   tile_e  = ctrl + 32;
  int*   tile_r0 = ctrl + 296;
  int*   tk_e    = ctrl + 560;
  float* tk_w    = (float*)(ctrl + 560 + 32768);
  int*   tok_of  = ctrl + 560 + 2 * 32768;
  float* w_of    = (float*)(ctrl + 560 + 3 * 32768);
  int*   inv     = ctrl + 560 + 4 * 32768;

  // y: prefer fp32 at [177,241) MB; fall back to bf16 overlaying dead xb/w1t if ws is small
  int use32 = (ws_size >= 242 * MB) ? 1 : 0;
  float*    y32 = (float*)(ws + 177 * MB);
  uint16_t* y16 = (uint16_t*)ws;                   // [0,32) MB — xb/w1t dead after gemm1

  hipMemsetAsync(counts, 0, 16 * sizeof(int), stream);

  k_cvt<<<4096, 256, 0, stream>>>(x, xb, (BTOK * DM) / 8);
  k_tr<<<dim3(DFF / 32, DM / 32, NE), dim3(32, 8), 0, stream>>>(w1, w1t, DM, DFF);
  k_tr<<<dim3(DM / 32, DFF / 32, NE), dim3(32, 8), 0, stream>>>(w2, w2t, DFF, DM);
  k_route<<<BTOK / 64, 256, 0, stream>>>(x, wg, counts, tk_e, tk_w);
  k_setup<<<1, 64, 0, stream>>>(counts, offsets, tile_e, tile_r0, ntiles);
  k_build<<<NPAIR / 256, 256, 0, stream>>>(tk_e, tk_w, offsets, cursors, tok_of, w_of, inv);
  k_gemm1<<<MAXTILES * (DFF / BN), 256, 0, stream>>>(xb, w1t, b1, tok_of, offsets,
                                                     tile_e, tile_r0, ntiles, hbuf);
  k_gemm2<<<MAXTILES * (DM / BN), 256, 0, stream>>>(hbuf, w2t, b2, w_of, offsets,
                                                    tile_e, tile_r0, ntiles, y32, y16, use32);
  k_combine<<<BTOK / 2, 256, 0, stream>>>(y32, y16, use32, inv, out);
}

// Round 5
// 392.718 us; speedup vs baseline: 2.5375x; 1.0875x over previous
//
#include <hip/hip_runtime.h>
#include <stdint.h>

#define BTOK 16384
#define DM   512
#define DFF  2048
#define NE   8
#define NPAIR (BTOK*2)
#define BM 128
#define BK 64
#define MAXTILES 264

typedef short s16x8 __attribute__((ext_vector_type(8)));   // 8 bf16 in 4 VGPRs
typedef float f32x4 __attribute__((ext_vector_type(4)));

// fp32 -> bf16 RNE (inputs finite)
__device__ __forceinline__ uint16_t f2b(float f) {
  uint32_t u = __float_as_uint(f);
  u += 0x7fff + ((u >> 16) & 1);
  return (uint16_t)(u >> 16);
}

// async global->LDS, 16B per lane; lds ptr must be wave-uniform base (HW adds lane*16)
__device__ __forceinline__ void g2l16(const void* gp, void* lp) {
  __builtin_amdgcn_global_load_lds(
      (__attribute__((address_space(1))) void*)(void*)gp,
      (__attribute__((address_space(3))) void*)lp, 16, 0, 0);
}

// ---------------- fp32 -> bf16 convert (8 elems/thread) ----------------
__global__ void k_cvt(const float* __restrict__ in, uint16_t* __restrict__ out, int n8) {
  int i = blockIdx.x * 256 + threadIdx.x;
  if (i >= n8) return;
  const float4* p = (const float4*)in + (size_t)i * 2;
  float4 a = p[0], b = p[1];
  uint16_t v[8] = {f2b(a.x), f2b(a.y), f2b(a.z), f2b(a.w),
                   f2b(b.x), f2b(b.y), f2b(b.z), f2b(b.w)};
  *(s16x8*)(out + (size_t)i * 8) = *(s16x8*)v;
}

// ---------- per-expert transpose+convert: in [E][R][C] fp32 -> out [E][C][R] bf16 ----------
__global__ void k_tr(const float* __restrict__ in, uint16_t* __restrict__ out, int R, int C) {
  __shared__ float t[32][33];
  int e = blockIdx.z;
  const float* src = in + (size_t)e * R * C;
  uint16_t* dst = out + (size_t)e * R * C;
  int c0 = blockIdx.x * 32, r0 = blockIdx.y * 32;
  int tx = threadIdx.x, ty = threadIdx.y;
#pragma unroll
  for (int j = 0; j < 4; j++)
    t[ty + j * 8][tx] = src[(size_t)(r0 + ty + j * 8) * C + c0 + tx];
  __syncthreads();
#pragma unroll
  for (int j = 0; j < 4; j++)
    dst[(size_t)(c0 + ty + j * 8) * R + r0 + tx] = f2b(t[tx][ty + j * 8]);
}

// ---- gate: wave-per-token x16, wg in registers, LDS histogram, 8 global atomics/block ----
__global__ __launch_bounds__(256) void k_route(const float* __restrict__ x,
                                               const float* __restrict__ wg,
                                               int* __restrict__ counts,
                                               int* __restrict__ tk_e, float* __restrict__ tk_w) {
  __shared__ int hist[NE];
  int tid = threadIdx.x, lane = tid & 63, wave = tid >> 6;
  if (tid < NE) hist[tid] = 0;
  __syncthreads();

  float wv[8][8];
#pragma unroll
  for (int j = 0; j < 8; j++) {
    const float4* wr = (const float4*)(wg + (size_t)(j * 64 + lane) * NE);
    float4 a = wr[0], b = wr[1];
    wv[j][0] = a.x; wv[j][1] = a.y; wv[j][2] = a.z; wv[j][3] = a.w;
    wv[j][4] = b.x; wv[j][5] = b.y; wv[j][6] = b.z; wv[j][7] = b.w;
  }

  int tok0 = blockIdx.x * 64 + wave * 16;
  for (int tt = 0; tt < 16; tt++) {
    int tok = tok0 + tt;
    const float* xr = x + (size_t)tok * DM;
    float xv[8];
#pragma unroll
    for (int j = 0; j < 8; j++) xv[j] = xr[j * 64 + lane];
    float acc[NE];
#pragma unroll
    for (int e = 0; e < NE; e++) acc[e] = 0.f;
#pragma unroll
    for (int j = 0; j < 8; j++)
#pragma unroll
      for (int e = 0; e < NE; e++) acc[e] += xv[j] * wv[j][e];
#pragma unroll
    for (int e = 0; e < NE; e++) {
#pragma unroll
      for (int off = 32; off > 0; off >>= 1) acc[e] += __shfl_xor(acc[e], off, 64);
    }
    if (lane == 0) {
      float mx = acc[0];
      for (int e = 1; e < NE; e++) mx = fmaxf(mx, acc[e]);
      float p[NE], s = 0.f;
      for (int e = 0; e < NE; e++) { p[e] = __expf(acc[e] - mx); s += p[e]; }
      float inv = 1.f / s;
      int e0 = 0; float v0 = p[0];
      for (int e = 1; e < NE; e++) if (p[e] > v0) { v0 = p[e]; e0 = e; }  // strict > = top_k tiebreak
      int e1 = -1; float v1 = -1.f;
      for (int e = 0; e < NE; e++) if (e != e0 && p[e] > v1) { v1 = p[e]; e1 = e; }
      tk_e[tok * 2]     = e0; tk_w[tok * 2]     = v0 * inv;
      tk_e[tok * 2 + 1] = e1; tk_w[tok * 2 + 1] = v1 * inv;
      atomicAdd(&hist[e0], 1);
      atomicAdd(&hist[e1], 1);
    }
  }
  __syncthreads();
  if (tid < NE) atomicAdd(&counts[tid], hist[tid]);
}

// ---------------- prefix sums + tile map ----------------
__global__ void k_setup(const int* __restrict__ counts, int* __restrict__ offsets,
                        int* __restrict__ tile_e, int* __restrict__ tile_r0, int* __restrict__ ntiles) {
  if (threadIdx.x != 0 || blockIdx.x != 0) return;
  int off = 0;
  for (int e = 0; e < NE; e++) { offsets[e] = off; off += counts[e]; }
  offsets[NE] = off;
  int nt = 0;
  for (int e = 0; e < NE; e++)
    for (int r = offsets[e]; r < offsets[e + 1]; r += BM) { tile_e[nt] = e; tile_r0[nt] = r; nt++; }
  *ntiles = nt;
}

// ------- build compact slot lists + inverse map -------
__global__ __launch_bounds__(256) void k_build(const int* __restrict__ tk_e, const float* __restrict__ tk_w,
                                               const int* __restrict__ offsets, int* __restrict__ cursors,
                                               int* __restrict__ tok_of, float* __restrict__ w_of,
                                               int* __restrict__ inv) {
  __shared__ int lcnt[NE], lbase[NE];
  int tid = threadIdx.x;
  int i = blockIdx.x * 256 + tid;
  if (tid < NE) lcnt[tid] = 0;
  __syncthreads();
  int e = tk_e[i];
  int local = atomicAdd(&lcnt[e], 1);
  __syncthreads();
  if (tid < NE) lbase[tid] = atomicAdd(&cursors[tid], lcnt[tid]);
  __syncthreads();
  int slot = offsets[e] + lbase[e] + local;
  tok_of[slot] = i >> 1;
  w_of[slot] = tk_w[i];
  inv[i] = slot;
}

// ---------------- GEMM1: h[slot][DFF] = relu(x[tok] @ W1[e] + b1[e]) ----------------
// tile 128x256, wave tile 64x128 (acc 4x8), LDS sA 16KB + sB 32KB, XOR swizzle
// grid 1-D: all 8 n-tiles of a row-tile share id%8 (same XCD)
__global__ __launch_bounds__(256, 2) void k_gemm1(
    const uint16_t* __restrict__ xb, const uint16_t* __restrict__ w1t,
    const float* __restrict__ b1,
    const int* __restrict__ tok_of, const int* __restrict__ offsets,
    const int* __restrict__ tile_e, const int* __restrict__ tile_r0,
    const int* __restrict__ ntiles, uint16_t* __restrict__ h) {
  __shared__ uint16_t smem[24576];          // sA 16KB | sB 32KB
  int id = blockIdx.x;
  int t = ((id >> 6) << 3) | (id & 7);
  int n0 = ((id >> 3) & 7) * 256;
  if (t >= *ntiles) return;
  int e = tile_e[t], row0 = tile_r0[t], end = offsets[e + 1];
  int tid = threadIdx.x, lane = tid & 63, wave = tid >> 6;
  int wr = (wave >> 1) * 64;                // m offset
  int wcb = (wave & 1) * 128;               // n offset (sB rows)
  uint16_t* sA = smem;
  uint16_t* sB = smem + 8192;

  int cofs = (((tid & 7) ^ ((tid >> 3) & 7))) * 8;   // swizzled source chunk
  int rw = tid >> 3;                                  // base row [0,32)
  int aofs[4];
#pragma unroll
  for (int it = 0; it < 4; it++) {
    int slot = row0 + it * 32 + rw; if (slot >= end) slot = end - 1;
    aofs[it] = tok_of[slot] * DM + cofs;
  }
  int bofs = rw * DM + cofs;
  const uint16_t* bb = w1t + (size_t)e * DFF * DM + (size_t)n0 * DM;

  f32x4 acc[4][8];
#pragma unroll
  for (int r = 0; r < 4; r++)
#pragma unroll
    for (int c = 0; c < 8; c++)
#pragma unroll
      for (int i = 0; i < 4; i++) acc[r][c][i] = 0.f;

  for (int k0 = 0; k0 < DM; k0 += BK) {
#pragma unroll
    for (int it = 0; it < 4; it++)
      g2l16(xb + aofs[it] + k0, sA + (size_t)(it * 256 + wave * 64) * 8);
#pragma unroll
    for (int it = 0; it < 8; it++)
      g2l16(bb + bofs + it * 32 * DM + k0, sB + (size_t)(it * 256 + wave * 64) * 8);
    __syncthreads();
#pragma unroll
    for (int ks = 0; ks < BK; ks += 32) {
      int cb = (ks >> 3) + (lane >> 4);
      int co = (cb ^ (lane & 7)) << 3;
      s16x8 af[4], bf[8];
#pragma unroll
      for (int r = 0; r < 4; r++) af[r] = *(const s16x8*)(sA + (wr + r * 16 + (lane & 15)) * BK + co);
#pragma unroll
      for (int c = 0; c < 8; c++) bf[c] = *(const s16x8*)(sB + (wcb + c * 16 + (lane & 15)) * BK + co);
#pragma unroll
      for (int r = 0; r < 4; r++)
#pragma unroll
        for (int c = 0; c < 8; c++)
          acc[r][c] = __builtin_amdgcn_mfma_f32_16x16x32_bf16(af[r], bf[c], acc[r][c], 0, 0, 0);
    }
    __syncthreads();
  }

  // epilogue: bias+relu -> bf16, two 32KB LDS repack phases (fits 48KB smem)
  float bv[8];
#pragma unroll
  for (int c = 0; c < 8; c++) bv[c] = b1[(size_t)e * DFF + n0 + wcb + c * 16 + (lane & 15)];
#pragma unroll
  for (int ch = 0; ch < 2; ch++) {
    uint16_t* myreg = smem + wave * 4096;   // per-wave 64x64 region
#pragma unroll
    for (int r = 0; r < 4; r++)
#pragma unroll
      for (int c2 = 0; c2 < 4; c2++) {
        int gc = ch * 4 + c2;
#pragma unroll
        for (int i = 0; i < 4; i++) {
          int row = r * 16 + (lane >> 4) * 4 + i;       // C/D: col=lane&15, row=quad*4+reg
          int col = c2 * 16 + (lane & 15);
          float v = fmaxf(acc[r][gc][i] + bv[gc], 0.f);
          myreg[row * 64 + col] = f2b(v);
        }
      }
    __syncthreads();
#pragma unroll
    for (int it = 0; it < 8; it++) {
      int chunk = it * 256 + tid;           // 128 rows x 2 strips x 8 col-chunks
      int row = chunk >> 4, rem = chunk & 15;
      int strip = rem >> 3, cw = (rem & 7) * 8;
      int slot = row0 + row;
      if (slot < end) {
        const uint16_t* src = smem + ((row >> 6) * 2 + strip) * 4096 + (row & 63) * 64 + cw;
        *(s16x8*)(h + (size_t)slot * DFF + n0 + strip * 128 + ch * 64 + cw) = *(const s16x8*)src;
      }
    }
    __syncthreads();
  }
}

// ---------------- GEMM2: y[slot] = w_of[slot] * (h[slot] @ W2[e] + b2[e]) ----------------
// tile 128x256, wave tile 64x128; no atomics
__global__ __launch_bounds__(256, 2) void k_gemm2(
    const uint16_t* __restrict__ h, const uint16_t* __restrict__ w2t,
    const float* __restrict__ b2,
    const float* __restrict__ w_of,
    const int* __restrict__ offsets,
    const int* __restrict__ tile_e, const int* __restrict__ tile_r0,
    const int* __restrict__ ntiles,
    float* __restrict__ y32, uint16_t* __restrict__ y16, int use32) {
  __shared__ uint16_t smem[24576];
  int id = blockIdx.x;
  int t = ((id >> 4) << 3) | (id & 7);
  int n0 = ((id >> 3) & 1) * 256;
  if (t >= *ntiles) return;
  int e = tile_e[t], row0 = tile_r0[t], end = offsets[e + 1];
  int tid = threadIdx.x, lane = tid & 63, wave = tid >> 6;
  int wr = (wave >> 1) * 64;
  int wcb = (wave & 1) * 128;
  uint16_t* sA = smem;
  uint16_t* sB = smem + 8192;

  int cofs = (((tid & 7) ^ ((tid >> 3) & 7))) * 8;
  int rw = tid >> 3;
  int aofs[4];
#pragma unroll
  for (int it = 0; it < 4; it++) {
    int slot = row0 + it * 32 + rw; if (slot >= end) slot = end - 1;
    aofs[it] = slot * DFF + cofs;
  }
  int bofs = rw * DFF + cofs;
  const uint16_t* bb = w2t + (size_t)e * DM * DFF + (size_t)n0 * DFF;

  f32x4 acc[4][8];
#pragma unroll
  for (int r = 0; r < 4; r++)
#pragma unroll
    for (int c = 0; c < 8; c++)
#pragma unroll
      for (int i = 0; i < 4; i++) acc[r][c][i] = 0.f;

  for (int k0 = 0; k0 < DFF; k0 += BK) {
#pragma unroll
    for (int it = 0; it < 4; it++)
      g2l16(h + aofs[it] + k0, sA + (size_t)(it * 256 + wave * 64) * 8);
#pragma unroll
    for (int it = 0; it < 8; it++)
      g2l16(bb + bofs + it * 32 * DFF + k0, sB + (size_t)(it * 256 + wave * 64) * 8);
    __syncthreads();
#pragma unroll
    for (int ks = 0; ks < BK; ks += 32) {
      int cb = (ks >> 3) + (lane >> 4);
      int co = (cb ^ (lane & 7)) << 3;
      s16x8 af[4], bf[8];
#pragma unroll
      for (int r = 0; r < 4; r++) af[r] = *(const s16x8*)(sA + (wr + r * 16 + (lane & 15)) * BK + co);
#pragma unroll
      for (int c = 0; c < 8; c++) bf[c] = *(const s16x8*)(sB + (wcb + c * 16 + (lane & 15)) * BK + co);
#pragma unroll
      for (int r = 0; r < 4; r++)
#pragma unroll
        for (int c = 0; c < 8; c++)
          acc[r][c] = __builtin_amdgcn_mfma_f32_16x16x32_bf16(af[r], bf[c], acc[r][c], 0, 0, 0);
    }
    __syncthreads();
  }

  float bv[8];
#pragma unroll
  for (int c = 0; c < 8; c++) bv[c] = b2[(size_t)e * DM + n0 + wcb + c * 16 + (lane & 15)];
#pragma unroll
  for (int r = 0; r < 4; r++)
#pragma unroll
    for (int i = 0; i < 4; i++) {
      int rowg = wr + r * 16 + (lane >> 4) * 4 + i;
      int slot = row0 + rowg;
      if (slot < end) {
        float wgt = w_of[slot];
        size_t base = (size_t)slot * DM + n0 + wcb + (lane & 15);
        if (use32) {
#pragma unroll
          for (int c = 0; c < 8; c++) y32[base + c * 16] = wgt * (acc[r][c][i] + bv[c]);
        } else {
#pragma unroll
          for (int c = 0; c < 8; c++) y16[base + c * 16] = f2b(wgt * (acc[r][c][i] + bv[c]));
        }
      }
    }
}

// ---------------- combine: out[tok] = y[slot0] + y[slot1] (weights pre-applied) ----------------
__global__ __launch_bounds__(256) void k_combine(const float* __restrict__ y32,
                                                 const uint16_t* __restrict__ y16, int use32,
                                                 const int* __restrict__ inv,
                                                 float* __restrict__ out) {
  int tid = threadIdx.x;
  int tok = blockIdx.x * 2 + (tid >> 7);
  int c4 = (tid & 127) * 4;
  int s0 = inv[tok * 2], s1 = inv[tok * 2 + 1];
  float4 o;
  if (use32) {
    const float4 a = *(const float4*)(y32 + (size_t)s0 * DM + c4);
    const float4 b = *(const float4*)(y32 + (size_t)s1 * DM + c4);
    o = make_float4(a.x + b.x, a.y + b.y, a.z + b.z, a.w + b.w);
  } else {
    const ushort4 a = *(const ushort4*)(y16 + (size_t)s0 * DM + c4);
    const ushort4 b = *(const ushort4*)(y16 + (size_t)s1 * DM + c4);
    o = make_float4(__uint_as_float((uint32_t)a.x << 16) + __uint_as_float((uint32_t)b.x << 16),
                    __uint_as_float((uint32_t)a.y << 16) + __uint_as_float((uint32_t)b.y << 16),
                    __uint_as_float((uint32_t)a.z << 16) + __uint_as_float((uint32_t)b.z << 16),
                    __uint_as_float((uint32_t)a.w << 16) + __uint_as_float((uint32_t)b.w << 16));
  }
  *(float4*)(out + (size_t)tok * DM + c4) = o;
}

extern "C" void kernel_launch(void* const* d_in, const int* in_sizes, int n_in,
                              void* d_out, int out_size, void* d_ws, size_t ws_size,
                              hipStream_t stream) {
  const float* x  = (const float*)d_in[0];
  const float* wg = (const float*)d_in[1];
  const float* w1 = (const float*)d_in[2];
  const float* b1 = (const float*)d_in[3];
  const float* w2 = (const float*)d_in[4];
  const float* b2 = (const float*)d_in[5];
  float* out = (float*)d_out;

  char* ws = (char*)d_ws;
  const size_t MB = 1024 * 1024;
  uint16_t* xb   = (uint16_t*)ws;                  // [0,16) MB
  uint16_t* w1t  = (uint16_t*)(ws + 16 * MB);      // [16,32) MB  [E][DFF][DM]
  uint16_t* w2t  = (uint16_t*)(ws + 32 * MB);      // [32,48) MB  [E][DM][DFF]
  uint16_t* hbuf = (uint16_t*)(ws + 48 * MB);      // [48,176) MB [NPAIR][DFF]
  int* ctrl = (int*)(ws + 176 * MB);               // [176,177) MB
  int*   counts  = ctrl;
  int*   cursors = ctrl + 8;
  int*   offsets = ctrl + 16;
  int*   ntiles  = ctrl + 25;
  int*   tile_e  = ctrl + 32;
  int*   tile_r0 = ctrl + 296;
  int*   tk_e    = ctrl + 560;
  float* tk_w    = (float*)(ctrl + 560 + 32768);
  int*   tok_of  = ctrl + 560 + 2 * 32768;
  float* w_of    = (float*)(ctrl + 560 + 3 * 32768);
  int*   inv     = ctrl + 560 + 4 * 32768;

  int use32 = (ws_size >= 242 * MB) ? 1 : 0;
  float*    y32 = (float*)(ws + 177 * MB);
  uint16_t* y16 = (uint16_t*)ws;                   // xb/w1t dead after gemm1

  hipMemsetAsync(counts, 0, 16 * sizeof(int), stream);

  k_cvt<<<4096, 256, 0, stream>>>(x, xb, (BTOK * DM) / 8);
  k_tr<<<dim3(DFF / 32, DM / 32, NE), dim3(32, 8), 0, stream>>>(w1, w1t, DM, DFF);
  k_tr<<<dim3(DM / 32, DFF / 32, NE), dim3(32, 8), 0, stream>>>(w2, w2t, DFF, DM);
  k_route<<<BTOK / 64, 256, 0, stream>>>(x, wg, counts, tk_e, tk_w);
  k_setup<<<1, 64, 0, stream>>>(counts, offsets, tile_e, tile_r0, ntiles);
  k_build<<<NPAIR / 256, 256, 0, stream>>>(tk_e, tk_w, offsets, cursors, tok_of, w_of, inv);
  k_gemm1<<<MAXTILES * 8, 256, 0, stream>>>(xb, w1t, b1, tok_of, offsets,
                                            tile_e, tile_r0, ntiles, hbuf);
  k_gemm2<<<MAXTILES * 2, 256, 0, stream>>>(hbuf, w2t, b2, w_of, offsets,
                                            tile_e, tile_r0, ntiles, y32, y16, use32);
  k_combine<<<BTOK / 2, 256, 0, stream>>>(y32, y16, use32, inv, out);
}

// Round 6
// 391.848 us; speedup vs baseline: 2.5432x; 1.0022x over previous
//
#include <hip/hip_runtime.h>
#include <stdint.h>

#define BTOK 16384
#define DM   512
#define DFF  2048
#define NE   8
#define NPAIR (BTOK*2)
#define BM 128
#define BK 64
#define MAXTILES 264
#define MAXTE 48          // max 128-row tiles per expert (count<=6144; actual ~32)

typedef short s16x8 __attribute__((ext_vector_type(8)));   // 8 bf16 in 4 VGPRs
typedef float f32x4 __attribute__((ext_vector_type(4)));

// fp32 -> bf16 RNE (inputs finite)
__device__ __forceinline__ uint16_t f2b(float f) {
  uint32_t u = __float_as_uint(f);
  u += 0x7fff + ((u >> 16) & 1);
  return (uint16_t)(u >> 16);
}

// async global->LDS, 16B per lane; lds ptr must be wave-uniform base (HW adds lane*16)
__device__ __forceinline__ void g2l16(const void* gp, void* lp) {
  __builtin_amdgcn_global_load_lds(
      (__attribute__((address_space(1))) void*)(void*)gp,
      (__attribute__((address_space(3))) void*)lp, 16, 0, 0);
}

// ---------------- fp32 -> bf16 convert (8 elems/thread) ----------------
__global__ void k_cvt(const float* __restrict__ in, uint16_t* __restrict__ out, int n8) {
  int i = blockIdx.x * 256 + threadIdx.x;
  if (i >= n8) return;
  const float4* p = (const float4*)in + (size_t)i * 2;
  float4 a = p[0], b = p[1];
  uint16_t v[8] = {f2b(a.x), f2b(a.y), f2b(a.z), f2b(a.w),
                   f2b(b.x), f2b(b.y), f2b(b.z), f2b(b.w)};
  *(s16x8*)(out + (size_t)i * 8) = *(s16x8*)v;
}

// ---------- per-expert transpose+convert: in [E][R][C] fp32 -> out [E][C][R] bf16 ----------
__global__ void k_tr(const float* __restrict__ in, uint16_t* __restrict__ out, int R, int C) {
  __shared__ float t[32][33];
  int e = blockIdx.z;
  const float* src = in + (size_t)e * R * C;
  uint16_t* dst = out + (size_t)e * R * C;
  int c0 = blockIdx.x * 32, r0 = blockIdx.y * 32;
  int tx = threadIdx.x, ty = threadIdx.y;
#pragma unroll
  for (int j = 0; j < 4; j++)
    t[ty + j * 8][tx] = src[(size_t)(r0 + ty + j * 8) * C + c0 + tx];
  __syncthreads();
#pragma unroll
  for (int j = 0; j < 4; j++)
    dst[(size_t)(c0 + ty + j * 8) * R + r0 + tx] = f2b(t[tx][ty + j * 8]);
}

// ---- gate: wave-per-token x16, wg in registers, LDS histogram, 8 global atomics/block ----
__global__ __launch_bounds__(256) void k_route(const float* __restrict__ x,
                                               const float* __restrict__ wg,
                                               int* __restrict__ counts,
                                               int* __restrict__ tk_e, float* __restrict__ tk_w) {
  __shared__ int hist[NE];
  int tid = threadIdx.x, lane = tid & 63, wave = tid >> 6;
  if (tid < NE) hist[tid] = 0;
  __syncthreads();

  float wv[8][8];
#pragma unroll
  for (int j = 0; j < 8; j++) {
    const float4* wr = (const float4*)(wg + (size_t)(j * 64 + lane) * NE);
    float4 a = wr[0], b = wr[1];
    wv[j][0] = a.x; wv[j][1] = a.y; wv[j][2] = a.z; wv[j][3] = a.w;
    wv[j][4] = b.x; wv[j][5] = b.y; wv[j][6] = b.z; wv[j][7] = b.w;
  }

  int tok0 = blockIdx.x * 64 + wave * 16;
  for (int tt = 0; tt < 16; tt++) {
    int tok = tok0 + tt;
    const float* xr = x + (size_t)tok * DM;
    float xv[8];
#pragma unroll
    for (int j = 0; j < 8; j++) xv[j] = xr[j * 64 + lane];
    float acc[NE];
#pragma unroll
    for (int e = 0; e < NE; e++) acc[e] = 0.f;
#pragma unroll
    for (int j = 0; j < 8; j++)
#pragma unroll
      for (int e = 0; e < NE; e++) acc[e] += xv[j] * wv[j][e];
#pragma unroll
    for (int e = 0; e < NE; e++) {
#pragma unroll
      for (int off = 32; off > 0; off >>= 1) acc[e] += __shfl_xor(acc[e], off, 64);
    }
    if (lane == 0) {
      float mx = acc[0];
      for (int e = 1; e < NE; e++) mx = fmaxf(mx, acc[e]);
      float p[NE], s = 0.f;
      for (int e = 0; e < NE; e++) { p[e] = __expf(acc[e] - mx); s += p[e]; }
      float inv = 1.f / s;
      int e0 = 0; float v0 = p[0];
      for (int e = 1; e < NE; e++) if (p[e] > v0) { v0 = p[e]; e0 = e; }  // strict > = top_k tiebreak
      int e1 = -1; float v1 = -1.f;
      for (int e = 0; e < NE; e++) if (e != e0 && p[e] > v1) { v1 = p[e]; e1 = e; }
      tk_e[tok * 2]     = e0; tk_w[tok * 2]     = v0 * inv;
      tk_e[tok * 2 + 1] = e1; tk_w[tok * 2 + 1] = v1 * inv;
      atomicAdd(&hist[e0], 1);
      atomicAdd(&hist[e1], 1);
    }
  }
  __syncthreads();
  if (tid < NE) atomicAdd(&counts[tid], hist[tid]);
}

// ---------------- prefix sums + tile map (+ per-expert tile start/count) ----------------
__global__ void k_setup(const int* __restrict__ counts, int* __restrict__ offsets,
                        int* __restrict__ tile_r0, int* __restrict__ tcnt, int* __restrict__ tstart) {
  if (threadIdx.x != 0 || blockIdx.x != 0) return;
  int off = 0;
  for (int e = 0; e < NE; e++) { offsets[e] = off; off += counts[e]; }
  offsets[NE] = off;
  int nt = 0;
  for (int e = 0; e < NE; e++) {
    tstart[e] = nt;
    int c = 0;
    for (int r = offsets[e]; r < offsets[e + 1]; r += BM) { tile_r0[nt] = r; nt++; c++; }
    tcnt[e] = c;
  }
}

// ------- build compact slot lists + inverse map -------
__global__ __launch_bounds__(256) void k_build(const int* __restrict__ tk_e, const float* __restrict__ tk_w,
                                               const int* __restrict__ offsets, int* __restrict__ cursors,
                                               int* __restrict__ tok_of, float* __restrict__ w_of,
                                               int* __restrict__ inv) {
  __shared__ int lcnt[NE], lbase[NE];
  int tid = threadIdx.x;
  int i = blockIdx.x * 256 + tid;
  if (tid < NE) lcnt[tid] = 0;
  __syncthreads();
  int e = tk_e[i];
  int local = atomicAdd(&lcnt[e], 1);
  __syncthreads();
  if (tid < NE) lbase[tid] = atomicAdd(&cursors[tid], lcnt[tid]);
  __syncthreads();
  int slot = offsets[e] + lbase[e] + local;
  tok_of[slot] = i >> 1;
  w_of[slot] = tk_w[i];
  inv[i] = slot;
}

// ---------------- GEMM1: h[slot][DFF] = relu(x[tok] @ W1[e] + b1[e]) ----------------
// tile 128x256, wave tile 64x128 (acc 4x8), LDS sA 16KB + sB 32KB, XOR swizzle
// XCD pinning: expert = blockIdx.x & 7 (id%8 -> XCD); per-expert W1 slice (2MB) stays L2-resident
__global__ __launch_bounds__(256, 2) void k_gemm1(
    const uint16_t* __restrict__ xb, const uint16_t* __restrict__ w1t,
    const float* __restrict__ b1,
    const int* __restrict__ tok_of, const int* __restrict__ offsets,
    const int* __restrict__ tile_r0, const int* __restrict__ tcnt, const int* __restrict__ tstart,
    uint16_t* __restrict__ h) {
  __shared__ uint16_t smem[24576];          // sA 16KB | sB 32KB
  int id = blockIdx.x;
  int e = id & 7, j = id >> 3;
  int ti = j >> 3;                          // tile within expert
  if (ti >= tcnt[e]) return;
  int row0 = tile_r0[tstart[e] + ti], end = offsets[e + 1];
  int n0 = (j & 7) * 256;
  int tid = threadIdx.x, lane = tid & 63, wave = tid >> 6;
  int wr = (wave >> 1) * 64;                // m offset
  int wcb = (wave & 1) * 128;               // n offset (sB rows)
  uint16_t* sA = smem;
  uint16_t* sB = smem + 8192;

  int cofs = (((tid & 7) ^ ((tid >> 3) & 7))) * 8;   // swizzled source chunk
  int rw = tid >> 3;                                  // base row [0,32)
  int aofs[4];
#pragma unroll
  for (int it = 0; it < 4; it++) {
    int slot = row0 + it * 32 + rw; if (slot >= end) slot = end - 1;
    aofs[it] = tok_of[slot] * DM + cofs;
  }
  int bofs = rw * DM + cofs;
  const uint16_t* bb = w1t + (size_t)e * DFF * DM + (size_t)n0 * DM;

  f32x4 acc[4][8];
#pragma unroll
  for (int r = 0; r < 4; r++)
#pragma unroll
    for (int c = 0; c < 8; c++)
#pragma unroll
      for (int i = 0; i < 4; i++) acc[r][c][i] = 0.f;

  for (int k0 = 0; k0 < DM; k0 += BK) {
#pragma unroll
    for (int it = 0; it < 4; it++)
      g2l16(xb + aofs[it] + k0, sA + (size_t)(it * 256 + wave * 64) * 8);
#pragma unroll
    for (int it = 0; it < 8; it++)
      g2l16(bb + bofs + it * 32 * DM + k0, sB + (size_t)(it * 256 + wave * 64) * 8);
    __syncthreads();
#pragma unroll
    for (int ks = 0; ks < BK; ks += 32) {
      int cb = (ks >> 3) + (lane >> 4);
      int co = (cb ^ (lane & 7)) << 3;
      s16x8 af[4], bf[8];
#pragma unroll
      for (int r = 0; r < 4; r++) af[r] = *(const s16x8*)(sA + (wr + r * 16 + (lane & 15)) * BK + co);
#pragma unroll
      for (int c = 0; c < 8; c++) bf[c] = *(const s16x8*)(sB + (wcb + c * 16 + (lane & 15)) * BK + co);
#pragma unroll
      for (int r = 0; r < 4; r++)
#pragma unroll
        for (int c = 0; c < 8; c++)
          acc[r][c] = __builtin_amdgcn_mfma_f32_16x16x32_bf16(af[r], bf[c], acc[r][c], 0, 0, 0);
    }
    __syncthreads();
  }

  // epilogue: bias+relu -> bf16, two 32KB LDS repack phases (fits 48KB smem)
  float bv[8];
#pragma unroll
  for (int c = 0; c < 8; c++) bv[c] = b1[(size_t)e * DFF + n0 + wcb + c * 16 + (lane & 15)];
#pragma unroll
  for (int ch = 0; ch < 2; ch++) {
    uint16_t* myreg = smem + wave * 4096;   // per-wave 64x64 region
#pragma unroll
    for (int r = 0; r < 4; r++)
#pragma unroll
      for (int c2 = 0; c2 < 4; c2++) {
        int gc = ch * 4 + c2;
#pragma unroll
        for (int i = 0; i < 4; i++) {
          int row = r * 16 + (lane >> 4) * 4 + i;       // C/D: col=lane&15, row=quad*4+reg
          int col = c2 * 16 + (lane & 15);
          float v = fmaxf(acc[r][gc][i] + bv[gc], 0.f);
          myreg[row * 64 + col] = f2b(v);
        }
      }
    __syncthreads();
#pragma unroll
    for (int it = 0; it < 8; it++) {
      int chunk = it * 256 + tid;           // 128 rows x 2 strips x 8 col-chunks
      int row = chunk >> 4, rem = chunk & 15;
      int strip = rem >> 3, cw = (rem & 7) * 8;
      int slot = row0 + row;
      if (slot < end) {
        const uint16_t* src = smem + ((row >> 6) * 2 + strip) * 4096 + (row & 63) * 64 + cw;
        *(s16x8*)(h + (size_t)slot * DFF + n0 + strip * 128 + ch * 64 + cw) = *(const s16x8*)src;
      }
    }
    __syncthreads();
  }
}

// ---------------- GEMM2: y[slot] = w_of[slot] * (h[slot] @ W2[e] + b2[e]) ----------------
// tile 128x256, wave tile 64x128; XCD pinning via expert = id&7; no atomics
__global__ __launch_bounds__(256, 2) void k_gemm2(
    const uint16_t* __restrict__ h, const uint16_t* __restrict__ w2t,
    const float* __restrict__ b2,
    const float* __restrict__ w_of,
    const int* __restrict__ offsets,
    const int* __restrict__ tile_r0, const int* __restrict__ tcnt, const int* __restrict__ tstart,
    float* __restrict__ y32, uint16_t* __restrict__ y16, int use32) {
  __shared__ uint16_t smem[24576];
  int id = blockIdx.x;
  int e = id & 7, j = id >> 3;
  int ti = j >> 1;
  if (ti >= tcnt[e]) return;
  int row0 = tile_r0[tstart[e] + ti], end = offsets[e + 1];
  int n0 = (j & 1) * 256;
  int tid = threadIdx.x, lane = tid & 63, wave = tid >> 6;
  int wr = (wave >> 1) * 64;
  int wcb = (wave & 1) * 128;
  uint16_t* sA = smem;
  uint16_t* sB = smem + 8192;

  int cofs = (((tid & 7) ^ ((tid >> 3) & 7))) * 8;
  int rw = tid >> 3;
  int aofs[4];
#pragma unroll
  for (int it = 0; it < 4; it++) {
    int slot = row0 + it * 32 + rw; if (slot >= end) slot = end - 1;
    aofs[it] = slot * DFF + cofs;
  }
  int bofs = rw * DFF + cofs;
  const uint16_t* bb = w2t + (size_t)e * DM * DFF + (size_t)n0 * DFF;

  f32x4 acc[4][8];
#pragma unroll
  for (int r = 0; r < 4; r++)
#pragma unroll
    for (int c = 0; c < 8; c++)
#pragma unroll
      for (int i = 0; i < 4; i++) acc[r][c][i] = 0.f;

  for (int k0 = 0; k0 < DFF; k0 += BK) {
#pragma unroll
    for (int it = 0; it < 4; it++)
      g2l16(h + aofs[it] + k0, sA + (size_t)(it * 256 + wave * 64) * 8);
#pragma unroll
    for (int it = 0; it < 8; it++)
      g2l16(bb + bofs + it * 32 * DFF + k0, sB + (size_t)(it * 256 + wave * 64) * 8);
    __syncthreads();
#pragma unroll
    for (int ks = 0; ks < BK; ks += 32) {
      int cb = (ks >> 3) + (lane >> 4);
      int co = (cb ^ (lane & 7)) << 3;
      s16x8 af[4], bf[8];
#pragma unroll
      for (int r = 0; r < 4; r++) af[r] = *(const s16x8*)(sA + (wr + r * 16 + (lane & 15)) * BK + co);
#pragma unroll
      for (int c = 0; c < 8; c++) bf[c] = *(const s16x8*)(sB + (wcb + c * 16 + (lane & 15)) * BK + co);
#pragma unroll
      for (int r = 0; r < 4; r++)
#pragma unroll
        for (int c = 0; c < 8; c++)
          acc[r][c] = __builtin_amdgcn_mfma_f32_16x16x32_bf16(af[r], bf[c], acc[r][c], 0, 0, 0);
    }
    __syncthreads();
  }

  float bv[8];
#pragma unroll
  for (int c = 0; c < 8; c++) bv[c] = b2[(size_t)e * DM + n0 + wcb + c * 16 + (lane & 15)];
#pragma unroll
  for (int r = 0; r < 4; r++)
#pragma unroll
    for (int i = 0; i < 4; i++) {
      int rowg = wr + r * 16 + (lane >> 4) * 4 + i;
      int slot = row0 + rowg;
      if (slot < end) {
        float wgt = w_of[slot];
        size_t base = (size_t)slot * DM + n0 + wcb + (lane & 15);
        if (use32) {
#pragma unroll
          for (int c = 0; c < 8; c++) y32[base + c * 16] = wgt * (acc[r][c][i] + bv[c]);
        } else {
#pragma unroll
          for (int c = 0; c < 8; c++) y16[base + c * 16] = f2b(wgt * (acc[r][c][i] + bv[c]));
        }
      }
    }
}

// ---------------- combine: out[tok] = y[slot0] + y[slot1] (weights pre-applied) ----------------
__global__ __launch_bounds__(256) void k_combine(const float* __restrict__ y32,
                                                 const uint16_t* __restrict__ y16, int use32,
                                                 const int* __restrict__ inv,
                                                 float* __restrict__ out) {
  int tid = threadIdx.x;
  int tok = blockIdx.x * 2 + (tid >> 7);
  int c4 = (tid & 127) * 4;
  int s0 = inv[tok * 2], s1 = inv[tok * 2 + 1];
  float4 o;
  if (use32) {
    const float4 a = *(const float4*)(y32 + (size_t)s0 * DM + c4);
    const float4 b = *(const float4*)(y32 + (size_t)s1 * DM + c4);
    o = make_float4(a.x + b.x, a.y + b.y, a.z + b.z, a.w + b.w);
  } else {
    const ushort4 a = *(const ushort4*)(y16 + (size_t)s0 * DM + c4);
    const ushort4 b = *(const ushort4*)(y16 + (size_t)s1 * DM + c4);
    o = make_float4(__uint_as_float((uint32_t)a.x << 16) + __uint_as_float((uint32_t)b.x << 16),
                    __uint_as_float((uint32_t)a.y << 16) + __uint_as_float((uint32_t)b.y << 16),
                    __uint_as_float((uint32_t)a.z << 16) + __uint_as_float((uint32_t)b.z << 16),
                    __uint_as_float((uint32_t)a.w << 16) + __uint_as_float((uint32_t)b.w << 16));
  }
  *(float4*)(out + (size_t)tok * DM + c4) = o;
}

extern "C" void kernel_launch(void* const* d_in, const int* in_sizes, int n_in,
                              void* d_out, int out_size, void* d_ws, size_t ws_size,
                              hipStream_t stream) {
  const float* x  = (const float*)d_in[0];
  const float* wg = (const float*)d_in[1];
  const float* w1 = (const float*)d_in[2];
  const float* b1 = (const float*)d_in[3];
  const float* w2 = (const float*)d_in[4];
  const float* b2 = (const float*)d_in[5];
  float* out = (float*)d_out;

  char* ws = (char*)d_ws;
  const size_t MB = 1024 * 1024;
  uint16_t* xb   = (uint16_t*)ws;                  // [0,16) MB
  uint16_t* w1t  = (uint16_t*)(ws + 16 * MB);      // [16,32) MB  [E][DFF][DM]
  uint16_t* w2t  = (uint16_t*)(ws + 32 * MB);      // [32,48) MB  [E][DM][DFF]
  uint16_t* hbuf = (uint16_t*)(ws + 48 * MB);      // [48,176) MB [NPAIR][DFF]
  int* ctrl = (int*)(ws + 176 * MB);               // [176,177) MB
  int*   counts  = ctrl;                 // 8
  int*   cursors = ctrl + 8;             // 8
  int*   offsets = ctrl + 16;            // 9
  int*   tcnt    = ctrl + 32;            // 8
  int*   tstart  = ctrl + 40;            // 8
  int*   tile_r0 = ctrl + 48;            // 264
  int*   tk_e    = ctrl + 320;
  float* tk_w    = (float*)(ctrl + 320 + 32768);
  int*   tok_of  = ctrl + 320 + 2 * 32768;
  float* w_of    = (float*)(ctrl + 320 + 3 * 32768);
  int*   inv     = ctrl + 320 + 4 * 32768;

  int use32 = (ws_size >= 242 * MB) ? 1 : 0;
  float*    y32 = (float*)(ws + 177 * MB);
  uint16_t* y16 = (uint16_t*)ws;                   // xb/w1t dead after gemm1

  hipMemsetAsync(counts, 0, 16 * sizeof(int), stream);

  k_cvt<<<4096, 256, 0, stream>>>(x, xb, (BTOK * DM) / 8);
  k_tr<<<dim3(DFF / 32, DM / 32, NE), dim3(32, 8), 0, stream>>>(w1, w1t, DM, DFF);
  k_tr<<<dim3(DM / 32, DFF / 32, NE), dim3(32, 8), 0, stream>>>(w2, w2t, DFF, DM);
  k_route<<<BTOK / 64, 256, 0, stream>>>(x, wg, counts, tk_e, tk_w);
  k_setup<<<1, 64, 0, stream>>>(counts, offsets, tile_r0, tcnt, tstart);
  k_build<<<NPAIR / 256, 256, 0, stream>>>(tk_e, tk_w, offsets, cursors, tok_of, w_of, inv);
  k_gemm1<<<NE * MAXTE * 8, 256, 0, stream>>>(xb, w1t, b1, tok_of, offsets,
                                              tile_r0, tcnt, tstart, hbuf);
  k_gemm2<<<NE * MAXTE * 2, 256, 0, stream>>>(hbuf, w2t, b2, w_of, offsets,
                                              tile_r0, tcnt, tstart, y32, y16, use32);
  k_combine<<<BTOK / 2, 256, 0, stream>>>(y32, y16, use32, inv, out);
}

// Round 7
// 382.070 us; speedup vs baseline: 2.6082x; 1.0256x over previous
//
#include <hip/hip_runtime.h>
#include <stdint.h>

#define BTOK 16384
#define DM   512
#define DFF  2048
#define NE   8
#define NPAIR (BTOK*2)
#define BM 128
#define MAXTE 48          // max 128-row tiles per expert (balanced routing: ~32)

typedef short s16x8 __attribute__((ext_vector_type(8)));   // 8 bf16 in 4 VGPRs
typedef float f32x4 __attribute__((ext_vector_type(4)));

// fp32 -> bf16 RNE (inputs finite)
__device__ __forceinline__ uint16_t f2b(float f) {
  uint32_t u = __float_as_uint(f);
  u += 0x7fff + ((u >> 16) & 1);
  return (uint16_t)(u >> 16);
}

// async global->LDS, 16B per lane; lds ptr must be wave-uniform base (HW adds lane*16)
__device__ __forceinline__ void g2l16(const void* gp, void* lp) {
  __builtin_amdgcn_global_load_lds(
      (__attribute__((address_space(1))) void*)(void*)gp,
      (__attribute__((address_space(3))) void*)lp, 16, 0, 0);
}

// ---------- merged transpose+convert: z<8 -> W1 [D][DFF]->[DFF][D], z>=8 -> W2 [DFF][D]->[D][DFF] ----------
__global__ void k_tr(const float* __restrict__ w1, const float* __restrict__ w2,
                     uint16_t* __restrict__ w1t, uint16_t* __restrict__ w2t) {
  __shared__ float t[32][33];
  int z = blockIdx.z, bx = blockIdx.x;
  int R, C, c0, r0;
  const float* src;
  uint16_t* dst;
  if (z < 8) { R = DM; C = DFF; c0 = (bx & 63) * 32; r0 = (bx >> 6) * 32;
               src = w1 + (size_t)z * R * C; dst = w1t + (size_t)z * R * C; }
  else       { R = DFF; C = DM; c0 = (bx & 15) * 32; r0 = (bx >> 4) * 32;
               src = w2 + (size_t)(z - 8) * R * C; dst = w2t + (size_t)(z - 8) * R * C; }
  int tx = threadIdx.x, ty = threadIdx.y;
#pragma unroll
  for (int j = 0; j < 4; j++)
    t[ty + j * 8][tx] = src[(size_t)(r0 + ty + j * 8) * C + c0 + tx];
  __syncthreads();
#pragma unroll
  for (int j = 0; j < 4; j++)
    dst[(size_t)(c0 + ty + j * 8) * R + r0 + tx] = f2b(t[tx][ty + j * 8]);
}

// ---- gate + x->bf16: wave-per-token x16, wg in registers, LDS histogram; then convert block's x slab ----
__global__ __launch_bounds__(256) void k_route(const float* __restrict__ x,
                                               const float* __restrict__ wg,
                                               int* __restrict__ counts,
                                               int* __restrict__ tk_e, float* __restrict__ tk_w,
                                               uint16_t* __restrict__ xb) {
  __shared__ int hist[NE];
  int tid = threadIdx.x, lane = tid & 63, wave = tid >> 6;
  if (tid < NE) hist[tid] = 0;
  __syncthreads();

  float wv[8][8];
#pragma unroll
  for (int j = 0; j < 8; j++) {
    const float4* wr = (const float4*)(wg + (size_t)(j * 64 + lane) * NE);
    float4 a = wr[0], b = wr[1];
    wv[j][0] = a.x; wv[j][1] = a.y; wv[j][2] = a.z; wv[j][3] = a.w;
    wv[j][4] = b.x; wv[j][5] = b.y; wv[j][6] = b.z; wv[j][7] = b.w;
  }

  int tok0 = blockIdx.x * 64 + wave * 16;
  for (int tt = 0; tt < 16; tt++) {
    int tok = tok0 + tt;
    const float* xr = x + (size_t)tok * DM;
    float xv[8];
#pragma unroll
    for (int j = 0; j < 8; j++) xv[j] = xr[j * 64 + lane];
    float acc[NE];
#pragma unroll
    for (int e = 0; e < NE; e++) acc[e] = 0.f;
#pragma unroll
    for (int j = 0; j < 8; j++)
#pragma unroll
      for (int e = 0; e < NE; e++) acc[e] += xv[j] * wv[j][e];
#pragma unroll
    for (int e = 0; e < NE; e++) {
#pragma unroll
      for (int off = 32; off > 0; off >>= 1) acc[e] += __shfl_xor(acc[e], off, 64);
    }
    if (lane == 0) {
      float mx = acc[0];
      for (int e = 1; e < NE; e++) mx = fmaxf(mx, acc[e]);
      float p[NE], s = 0.f;
      for (int e = 0; e < NE; e++) { p[e] = __expf(acc[e] - mx); s += p[e]; }
      float inv = 1.f / s;
      int e0 = 0; float v0 = p[0];
      for (int e = 1; e < NE; e++) if (p[e] > v0) { v0 = p[e]; e0 = e; }  // strict > = top_k tiebreak
      int e1 = -1; float v1 = -1.f;
      for (int e = 0; e < NE; e++) if (e != e0 && p[e] > v1) { v1 = p[e]; e1 = e; }
      tk_e[tok * 2]     = e0; tk_w[tok * 2]     = v0 * inv;
      tk_e[tok * 2 + 1] = e1; tk_w[tok * 2 + 1] = v1 * inv;
      atomicAdd(&hist[e0], 1);
      atomicAdd(&hist[e1], 1);
    }
  }
  // convert this block's 64-token slab (L2-hot) to bf16
  const float* xs = x + (size_t)blockIdx.x * 32768;
  uint16_t* xd = xb + (size_t)blockIdx.x * 32768;
#pragma unroll
  for (int i = 0; i < 16; i++) {
    int o = i * 2048 + tid * 8;
    float4 a = *(const float4*)(xs + o);
    float4 b = *(const float4*)(xs + o + 4);
    uint16_t v[8] = {f2b(a.x), f2b(a.y), f2b(a.z), f2b(a.w),
                     f2b(b.x), f2b(b.y), f2b(b.z), f2b(b.w)};
    *(s16x8*)(xd + o) = *(s16x8*)v;
  }
  __syncthreads();
  if (tid < NE) atomicAdd(&counts[tid], hist[tid]);
}

// ---------------- prefix sums + tile map (+ per-expert tile start/count) ----------------
__global__ void k_setup(const int* __restrict__ counts, int* __restrict__ offsets,
                        int* __restrict__ tile_r0, int* __restrict__ tcnt, int* __restrict__ tstart) {
  if (threadIdx.x != 0 || blockIdx.x != 0) return;
  int off = 0;
  for (int e = 0; e < NE; e++) { offsets[e] = off; off += counts[e]; }
  offsets[NE] = off;
  int nt = 0;
  for (int e = 0; e < NE; e++) {
    tstart[e] = nt;
    int c = 0;
    for (int r = offsets[e]; r < offsets[e + 1]; r += BM) { tile_r0[nt] = r; nt++; c++; }
    tcnt[e] = c;
  }
}

// ------- build compact slot lists + inverse map -------
__global__ __launch_bounds__(256) void k_build(const int* __restrict__ tk_e, const float* __restrict__ tk_w,
                                               const int* __restrict__ offsets, int* __restrict__ cursors,
                                               int* __restrict__ tok_of, float* __restrict__ w_of,
                                               int* __restrict__ inv) {
  __shared__ int lcnt[NE], lbase[NE];
  int tid = threadIdx.x;
  int i = blockIdx.x * 256 + tid;
  if (tid < NE) lcnt[tid] = 0;
  __syncthreads();
  int e = tk_e[i];
  int local = atomicAdd(&lcnt[e], 1);
  __syncthreads();
  if (tid < NE) lbase[tid] = atomicAdd(&cursors[tid], lcnt[tid]);
  __syncthreads();
  int slot = offsets[e] + lbase[e] + local;
  tok_of[slot] = i >> 1;
  w_of[slot] = tk_w[i];
  inv[i] = slot;
}

// ============ GEMM K-loop: 128x256 tile, BK=32, DOUBLE-BUFFERED prefetch ============
// LDS per buffer: sA 128x32 (8KB) + sB 256x32 (16KB); 2 buffers = 48KB.
// slot swizzle: LDS k-chunk slot s holds global chunk s ^ ((row>>1)&3)  -> frag reads 2-way max (free).
// Loop: sync -> issue prefetch(k+1, buf q) -> compute(buf p). Load latency hidden behind compute.

// ---------------- GEMM1: h[slot][DFF] = relu(x[tok] @ W1[e] + b1[e]) ----------------
__global__ __launch_bounds__(256, 2) void k_gemm1(
    const uint16_t* __restrict__ xb, const uint16_t* __restrict__ w1t,
    const float* __restrict__ b1,
    const int* __restrict__ tok_of, const int* __restrict__ offsets,
    const int* __restrict__ tile_r0, const int* __restrict__ tcnt, const int* __restrict__ tstart,
    uint16_t* __restrict__ h) {
  __shared__ uint16_t smem[24576];          // 2 x 12288 elems
  int id = blockIdx.x;
  int e = id & 7, j = id >> 3;              // XCD pinning: expert e -> XCD e
  int ti = j >> 3;
  if (ti >= tcnt[e]) return;
  int row0 = tile_r0[tstart[e] + ti], end = offsets[e + 1];
  int n0 = (j & 7) * 256;
  int tid = threadIdx.x, lane = tid & 63, wave = tid >> 6;
  int wr = (wave >> 1) * 64, wcb = (wave & 1) * 128;

  int aof[2];
#pragma unroll
  for (int it = 0; it < 2; it++) {
    int ci = it * 256 + tid;                // 512 A-chunks: row = ci>>2, slot = ci&3
    int row = ci >> 2;
    int c = (ci & 3) ^ ((row >> 1) & 3);
    int slot = row0 + row; if (slot >= end) slot = end - 1;
    aof[it] = tok_of[slot] * DM + c * 8;
  }
  int bof[4];
#pragma unroll
  for (int it = 0; it < 4; it++) {
    int ci = it * 256 + tid;                // 1024 B-chunks
    int row = ci >> 2;
    int c = (ci & 3) ^ ((row >> 1) & 3);
    bof[it] = row * DM + c * 8;
  }
  const uint16_t* bb = w1t + (size_t)e * DFF * DM + (size_t)n0 * DM;
  int sfrag = (lane >> 4) ^ ((lane >> 1) & 3);    // frag slot key (row bits1-2 = lane bits1-2)

  f32x4 acc[4][8];
#pragma unroll
  for (int r = 0; r < 4; r++)
#pragma unroll
    for (int c = 0; c < 8; c++)
#pragma unroll
      for (int i = 0; i < 4; i++) acc[r][c][i] = 0.f;

  // prologue: stage k=0 into buffer 0
#pragma unroll
  for (int it = 0; it < 2; it++)
    g2l16(xb + aof[it], smem + (size_t)(it * 256 + wave * 64) * 8);
#pragma unroll
  for (int it = 0; it < 4; it++)
    g2l16(bb + bof[it], smem + 4096 + (size_t)(it * 256 + wave * 64) * 8);

  int p = 0;
  for (int k0 = 0; k0 < DM; k0 += 32) {
    __syncthreads();                        // buf p ready (loads issued one compute-phase ago)
    int kn = k0 + 32, q = p ^ 1;
    if (kn < DM) {                          // prefetch next tile; overlaps compute below
#pragma unroll
      for (int it = 0; it < 2; it++)
        g2l16(xb + aof[it] + kn, smem + (size_t)q * 12288 + (size_t)(it * 256 + wave * 64) * 8);
#pragma unroll
      for (int it = 0; it < 4; it++)
        g2l16(bb + bof[it] + kn, smem + (size_t)q * 12288 + 4096 + (size_t)(it * 256 + wave * 64) * 8);
    }
    const uint16_t* sA = smem + (size_t)p * 12288;
    const uint16_t* sB = sA + 4096;
    s16x8 af[4], bf[8];
#pragma unroll
    for (int r = 0; r < 4; r++)
      af[r] = *(const s16x8*)(sA + (wr + r * 16 + (lane & 15)) * 32 + sfrag * 8);
#pragma unroll
    for (int c = 0; c < 8; c++)
      bf[c] = *(const s16x8*)(sB + (wcb + c * 16 + (lane & 15)) * 32 + sfrag * 8);
#pragma unroll
    for (int r = 0; r < 4; r++)
#pragma unroll
      for (int c = 0; c < 8; c++)
        acc[r][c] = __builtin_amdgcn_mfma_f32_16x16x32_bf16(af[r], bf[c], acc[r][c], 0, 0, 0);
    p = q;
  }
  __syncthreads();

  // epilogue: bias+relu -> bf16, two 32KB LDS repack phases
  float bv[8];
#pragma unroll
  for (int c = 0; c < 8; c++) bv[c] = b1[(size_t)e * DFF + n0 + wcb + c * 16 + (lane & 15)];
#pragma unroll
  for (int ch = 0; ch < 2; ch++) {
    uint16_t* myreg = smem + wave * 4096;   // per-wave 64x64 region
#pragma unroll
    for (int r = 0; r < 4; r++)
#pragma unroll
      for (int c2 = 0; c2 < 4; c2++) {
        int gc = ch * 4 + c2;
#pragma unroll
        for (int i = 0; i < 4; i++) {
          int row = r * 16 + (lane >> 4) * 4 + i;       // C/D: col=lane&15, row=quad*4+reg
          int col = c2 * 16 + (lane & 15);
          float v = fmaxf(acc[r][gc][i] + bv[gc], 0.f);
          myreg[row * 64 + col] = f2b(v);
        }
      }
    __syncthreads();
#pragma unroll
    for (int it = 0; it < 8; it++) {
      int chunk = it * 256 + tid;           // 128 rows x 2 strips x 8 col-chunks
      int row = chunk >> 4, rem = chunk & 15;
      int strip = rem >> 3, cw = (rem & 7) * 8;
      int slot = row0 + row;
      if (slot < end) {
        const uint16_t* src = smem + ((row >> 6) * 2 + strip) * 4096 + (row & 63) * 64 + cw;
        *(s16x8*)(h + (size_t)slot * DFF + n0 + strip * 128 + ch * 64 + cw) = *(const s16x8*)src;
      }
    }
    __syncthreads();
  }
}

// ---------------- GEMM2: y[slot] = w_of[slot] * (h[slot] @ W2[e] + b2[e]) ----------------
__global__ __launch_bounds__(256, 2) void k_gemm2(
    const uint16_t* __restrict__ h, const uint16_t* __restrict__ w2t,
    const float* __restrict__ b2,
    const float* __restrict__ w_of,
    const int* __restrict__ offsets,
    const int* __restrict__ tile_r0, const int* __restrict__ tcnt, const int* __restrict__ tstart,
    float* __restrict__ y32) {
  __shared__ uint16_t smem[24576];
  int id = blockIdx.x;
  int e = id & 7, j = id >> 3;
  int ti = j >> 1;
  if (ti >= tcnt[e]) return;
  int row0 = tile_r0[tstart[e] + ti], end = offsets[e + 1];
  int n0 = (j & 1) * 256;
  int tid = threadIdx.x, lane = tid & 63, wave = tid >> 6;
  int wr = (wave >> 1) * 64, wcb = (wave & 1) * 128;

  int aof[2];
#pragma unroll
  for (int it = 0; it < 2; it++) {
    int ci = it * 256 + tid;
    int row = ci >> 2;
    int c = (ci & 3) ^ ((row >> 1) & 3);
    int slot = row0 + row; if (slot >= end) slot = end - 1;
    aof[it] = slot * DFF + c * 8;
  }
  int bof[4];
#pragma unroll
  for (int it = 0; it < 4; it++) {
    int ci = it * 256 + tid;
    int row = ci >> 2;
    int c = (ci & 3) ^ ((row >> 1) & 3);
    bof[it] = row * DFF + c * 8;
  }
  const uint16_t* bb = w2t + (size_t)e * DM * DFF + (size_t)n0 * DFF;
  int sfrag = (lane >> 4) ^ ((lane >> 1) & 3);

  f32x4 acc[4][8];
#pragma unroll
  for (int r = 0; r < 4; r++)
#pragma unroll
    for (int c = 0; c < 8; c++)
#pragma unroll
      for (int i = 0; i < 4; i++) acc[r][c][i] = 0.f;

#pragma unroll
  for (int it = 0; it < 2; it++)
    g2l16(h + aof[it], smem + (size_t)(it * 256 + wave * 64) * 8);
#pragma unroll
  for (int it = 0; it < 4; it++)
    g2l16(bb + bof[it], smem + 4096 + (size_t)(it * 256 + wave * 64) * 8);

  int p = 0;
  for (int k0 = 0; k0 < DFF; k0 += 32) {
    __syncthreads();
    int kn = k0 + 32, q = p ^ 1;
    if (kn < DFF) {
#pragma unroll
      for (int it = 0; it < 2; it++)
        g2l16(h + aof[it] + kn, smem + (size_t)q * 12288 + (size_t)(it * 256 + wave * 64) * 8);
#pragma unroll
      for (int it = 0; it < 4; it++)
        g2l16(bb + bof[it] + kn, smem + (size_t)q * 12288 + 4096 + (size_t)(it * 256 + wave * 64) * 8);
    }
    const uint16_t* sA = smem + (size_t)p * 12288;
    const uint16_t* sB = sA + 4096;
    s16x8 af[4], bf[8];
#pragma unroll
    for (int r = 0; r < 4; r++)
      af[r] = *(const s16x8*)(sA + (wr + r * 16 + (lane & 15)) * 32 + sfrag * 8);
#pragma unroll
    for (int c = 0; c < 8; c++)
      bf[c] = *(const s16x8*)(sB + (wcb + c * 16 + (lane & 15)) * 32 + sfrag * 8);
#pragma unroll
    for (int r = 0; r < 4; r++)
#pragma unroll
      for (int c = 0; c < 8; c++)
        acc[r][c] = __builtin_amdgcn_mfma_f32_16x16x32_bf16(af[r], bf[c], acc[r][c], 0, 0, 0);
    p = q;
  }

  float bv[8];
#pragma unroll
  for (int c = 0; c < 8; c++) bv[c] = b2[(size_t)e * DM + n0 + wcb + c * 16 + (lane & 15)];
#pragma unroll
  for (int r = 0; r < 4; r++)
#pragma unroll
    for (int i = 0; i < 4; i++) {
      int rowg = wr + r * 16 + (lane >> 4) * 4 + i;
      int slot = row0 + rowg;
      if (slot < end) {
        float wgt = w_of[slot];
        size_t base = (size_t)slot * DM + n0 + wcb + (lane & 15);
#pragma unroll
        for (int c = 0; c < 8; c++) y32[base + c * 16] = wgt * (acc[r][c][i] + bv[c]);
      }
    }
}

// ---------------- combine: out[tok] = y[slot0] + y[slot1] (weights pre-applied) ----------------
__global__ __launch_bounds__(256) void k_combine(const float* __restrict__ y32,
                                                 const int* __restrict__ inv,
                                                 float* __restrict__ out) {
  int tid = threadIdx.x;
  int tok = blockIdx.x * 2 + (tid >> 7);
  int c4 = (tid & 127) * 4;
  int s0 = inv[tok * 2], s1 = inv[tok * 2 + 1];
  const float4 a = *(const float4*)(y32 + (size_t)s0 * DM + c4);
  const float4 b = *(const float4*)(y32 + (size_t)s1 * DM + c4);
  *(float4*)(out + (size_t)tok * DM + c4) = make_float4(a.x + b.x, a.y + b.y, a.z + b.z, a.w + b.w);
}

extern "C" void kernel_launch(void* const* d_in, const int* in_sizes, int n_in,
                              void* d_out, int out_size, void* d_ws, size_t ws_size,
                              hipStream_t stream) {
  const float* x  = (const float*)d_in[0];
  const float* wg = (const float*)d_in[1];
  const float* w1 = (const float*)d_in[2];
  const float* b1 = (const float*)d_in[3];
  const float* w2 = (const float*)d_in[4];
  const float* b2 = (const float*)d_in[5];
  float* out = (float*)d_out;

  char* ws = (char*)d_ws;
  const size_t MB = 1024 * 1024;
  uint16_t* xb   = (uint16_t*)ws;                  // [0,16) MB
  uint16_t* w1t  = (uint16_t*)(ws + 16 * MB);      // [16,32) MB  [E][DFF][DM]
  uint16_t* w2t  = (uint16_t*)(ws + 32 * MB);      // [32,48) MB  [E][DM][DFF]
  uint16_t* hbuf = (uint16_t*)(ws + 48 * MB);      // [48,176) MB [NPAIR][DFF]
  int* ctrl = (int*)(ws + 176 * MB);               // [176,177) MB
  int*   counts  = ctrl;                 // 8
  int*   cursors = ctrl + 8;             // 8
  int*   offsets = ctrl + 16;            // 9
  int*   tcnt    = ctrl + 32;            // 8
  int*   tstart  = ctrl + 40;            // 8
  int*   tile_r0 = ctrl + 48;            // 384
  int*   tk_e    = ctrl + 512;
  float* tk_w    = (float*)(ctrl + 512 + 32768);
  int*   tok_of  = ctrl + 512 + 2 * 32768;
  float* w_of    = (float*)(ctrl + 512 + 3 * 32768);
  int*   inv     = ctrl + 512 + 4 * 32768;
  float* y32     = (float*)(ws + 177 * MB);        // [177,241) MB fp32 [NPAIR][DM]

  hipMemsetAsync(counts, 0, 16 * sizeof(int), stream);

  k_route<<<BTOK / 64, 256, 0, stream>>>(x, wg, counts, tk_e, tk_w, xb);
  k_tr<<<dim3(1024, 1, 16), dim3(32, 8), 0, stream>>>(w1, w2, w1t, w2t);
  k_setup<<<1, 64, 0, stream>>>(counts, offsets, tile_r0, tcnt, tstart);
  k_build<<<NPAIR / 256, 256, 0, stream>>>(tk_e, tk_w, offsets, cursors, tok_of, w_of, inv);
  k_gemm1<<<NE * MAXTE * 8, 256, 0, stream>>>(xb, w1t, b1, tok_of, offsets,
                                              tile_r0, tcnt, tstart, hbuf);
  k_gemm2<<<NE * MAXTE * 2, 256, 0, stream>>>(hbuf, w2t, b2, w_of, offsets,
                                              tile_r0, tcnt, tstart, y32);
  k_combine<<<BTOK / 2, 256, 0, stream>>>(y32, inv, out);
}